// Round 4
// baseline (954.301 us; speedup 1.0000x reference)
//
#include <hip/hip_runtime.h>

// RoIHeads pipeline: roi_align -> FC1(relu) -> FC2(relu) -> cls/box heads ->
// softmax/decode/clip/mask -> per-class NMS.
//
// R4: GEMM1 moves to bf16 MFMA with 3-term split-fp32 (Ootomo-style):
//   a = a1+a2+a3 (bf16 each), C = sum of 6 MFMA products -> ~fp32 accuracy.
//   roi_align emits the 3 A-planes directly; conv_w1_k builds permuted,
//   TRANSPOSED B-planes [n][k'] so MFMA frag reads are contiguous 16B.
//   LDS tiles use pitch-40 bf16 rows => all b128 reads/writes uniform 8-slot
//   (conflict-free). Split-K=8 -> 512 blocks (2/CU). GEMM2 stays fp32 (R3).
// ws use: ~197 MB.

#define NEGV -1000000000.0f

typedef __attribute__((ext_vector_type(8))) short short8v;  // 8 bf16 (4 VGPR)
typedef __attribute__((ext_vector_type(4))) float f32x4;

#define KDIM 12544
#define PL   (1024 * 12544)   // plane elems (1024 padded rows)

__device__ __forceinline__ unsigned short to_bf16(float f) {
    unsigned u = __float_as_uint(f);
    unsigned r = u + 0x7FFFu + ((u >> 16) & 1u);   // RNE
    return (unsigned short)(r >> 16);
}
__device__ __forceinline__ float bf2f(unsigned short s) {
    return __uint_as_float((unsigned)s << 16);
}

// ---------------- RoI align + 3-way bf16 split ----------------
// grid = (49, 1000), block 256 (thread=channel); A-planes [1024][12544] bf16,
// k' = p*256 + c
__global__ __launch_bounds__(256) void roi_align_split3(const float* __restrict__ feat,
    const float* __restrict__ prop, unsigned short* __restrict__ Ap)
{
    int n = blockIdx.y;
    int p = blockIdx.x;
    int my = p / 7, mx = p % 7;
    float x1 = prop[n * 4 + 0] * 0.0625f;
    float y1 = prop[n * 4 + 1] * 0.0625f;
    float x2 = prop[n * 4 + 2] * 0.0625f;
    float y2 = prop[n * 4 + 3] * 0.0625f;
    float rw = fmaxf(x2 - x1, 1.0f), rh = fmaxf(y2 - y1, 1.0f);
    float y = y1 + ((float)my + 0.5f) * (rh / 7.0f);
    float x = x1 + ((float)mx + 0.5f) * (rw / 7.0f);
    bool oob = (y < -1.0f) || (y > 50.0f) || (x < -1.0f) || (x > 50.0f);
    y = fminf(fmaxf(y, 0.0f), 49.0f);
    x = fminf(fmaxf(x, 0.0f), 49.0f);
    int y0 = (int)floorf(y), x0 = (int)floorf(x);
    int y1i = min(y0 + 1, 49), x1i = min(x0 + 1, 49);
    float ly = y - (float)y0, lx = x - (float)x0;
    float hy = 1.0f - ly, hx = 1.0f - lx;
    int c = threadIdx.x;
    float v = feat[(y0 * 50 + x0) * 256 + c] * (hy * hx)
            + feat[(y0 * 50 + x1i) * 256 + c] * (hy * lx)
            + feat[(y1i * 50 + x0) * 256 + c] * (ly * hx)
            + feat[(y1i * 50 + x1i) * 256 + c] * (ly * lx);
    if (oob) v = 0.0f;
    unsigned short s1 = to_bf16(v);  float r  = v - bf2f(s1);
    unsigned short s2 = to_bf16(r);  float r2 = r - bf2f(s2);
    unsigned short s3 = to_bf16(r2);
    size_t o = (size_t)n * KDIM + p * 256 + c;
    Ap[o] = s1; Ap[PL + o] = s2; Ap[2 * (size_t)PL + o] = s3;
}

// zero rows 1000..1023 of the 3 A-planes. grid 441 x 256 (=112896 chunks of 8)
__global__ __launch_bounds__(256) void zero_padA(unsigned short* __restrict__ Ap)
{
    int id = blockIdx.x * 256 + threadIdx.x;     // < 3*24*1568
    int p = id / 37632;
    int rem = id - p * 37632;
    int r = rem / 1568, c8 = rem - r * 1568;
    *(uint4*)&Ap[(size_t)p * PL + (size_t)(1000 + r) * KDIM + c8 * 8] =
        make_uint4(0, 0, 0, 0);
}

// ---------------- w1 -> 3 bf16 planes, permuted + transposed ----------------
// Bt[p][n][k'] = split_p(w1[(k'&255)*49 + (k'>>8)][n]). grid (196,16), 256 thr.
__global__ __launch_bounds__(256) void conv_w1_k(const float* __restrict__ w1,
    unsigned short* __restrict__ Bt)
{
    __shared__ unsigned short T[3][64][72];   // pad 72: transpose reads cheap
    int k0 = blockIdx.x * 64;
    int n0 = blockIdx.y * 64;
    int t = threadIdx.x;
#pragma unroll
    for (int j = 0; j < 16; ++j) {
        int idx = t + 256 * j;
        int n_l = idx & 63, k_l = idx >> 6;
        int kp = k0 + k_l;
        int orow = (kp & 255) * 49 + (kp >> 8);
        float v = w1[(size_t)orow * 1024 + n0 + n_l];
        unsigned short s1 = to_bf16(v);  float r  = v - bf2f(s1);
        unsigned short s2 = to_bf16(r);  float r2 = r - bf2f(s2);
        T[0][k_l][n_l] = s1;
        T[1][k_l][n_l] = s2;
        T[2][k_l][n_l] = to_bf16(r2);
    }
    __syncthreads();
#pragma unroll
    for (int p = 0; p < 3; ++p)
#pragma unroll
        for (int jj = 0; jj < 2; ++jj) {
            int w = t + 256 * jj;            // 0..511
            int n_l = w >> 3, kg = w & 7;
            short8v pk;
#pragma unroll
            for (int e = 0; e < 8; ++e) pk[e] = (short)T[p][kg * 8 + e][n_l];
            *(short8v*)&Bt[(size_t)p * PL + (size_t)(n0 + n_l) * KDIM + k0 + kg * 8] = pk;
        }
}

// ---------------- split-3 bf16 MFMA GEMM (GEMM1) ----------------
// part[z][1024][1024] = sum_{6 plane pairs} A_i[128-tile] @ B_j. BM=BN=128,
// BK=32, 256 thr = 4 waves (2x2 of 64x64), 16x16x32 MFMA, split-K=8.
// grid (8, 8, 8) = (col, row, z). LDS pitch 40 bf16 -> conflict-free b128.
__global__ __launch_bounds__(256, 2) void gemm_mfma_split3(
    const unsigned short* __restrict__ Ap, const unsigned short* __restrict__ Bp,
    float* __restrict__ part, int Ks)
{
    __shared__ unsigned short As[3][128][40];
    __shared__ unsigned short Bs[3][128][40];
    int t = threadIdx.x;
    int col0 = blockIdx.x * 128;
    int row0 = blockIdx.y * 128;
    int kOff = blockIdx.z * Ks;

    int ar = t >> 2;          // 0..63 (staging row; +64 for second half)
    int ac = t & 3;           // 16B chunk within 32-k row
    uint4 pa[3][2], pb[3][2];

    auto loadTiles = [&](int k0) {
        int kpos = kOff + k0 + ac * 8;
#pragma unroll
        for (int p = 0; p < 3; ++p) {
            const unsigned short* aB = Ap + (size_t)p * PL;
            const unsigned short* bB = Bp + (size_t)p * PL;
            pa[p][0] = *(const uint4*)&aB[(size_t)(row0 + ar) * KDIM + kpos];
            pa[p][1] = *(const uint4*)&aB[(size_t)(row0 + ar + 64) * KDIM + kpos];
            pb[p][0] = *(const uint4*)&bB[(size_t)(col0 + ar) * KDIM + kpos];
            pb[p][1] = *(const uint4*)&bB[(size_t)(col0 + ar + 64) * KDIM + kpos];
        }
    };
    auto storeTiles = [&]() {
#pragma unroll
        for (int p = 0; p < 3; ++p) {
            *(uint4*)&As[p][ar][ac * 8]      = pa[p][0];
            *(uint4*)&As[p][ar + 64][ac * 8] = pa[p][1];
            *(uint4*)&Bs[p][ar][ac * 8]      = pb[p][0];
            *(uint4*)&Bs[p][ar + 64][ac * 8] = pb[p][1];
        }
    };

    int lane = t & 63;
    int ln = lane & 15, g = lane >> 4;
    int w = t >> 6;
    int wr = (w >> 1) * 64, wc = (w & 1) * 64;

    f32x4 acc[4][4] = {};

    loadTiles(0);
    for (int k0 = 0; k0 < Ks; k0 += 32) {
        __syncthreads();
        storeTiles();
        __syncthreads();
        if (k0 + 32 < Ks) loadTiles(k0 + 32);

        short8v bfr[3][4];
#pragma unroll
        for (int p = 0; p < 3; ++p)
#pragma unroll
            for (int fc = 0; fc < 4; ++fc)
                bfr[p][fc] = *(const short8v*)&Bs[p][wc + fc * 16 + ln][g * 8];
#pragma unroll
        for (int fr = 0; fr < 4; ++fr) {
            short8v a0 = *(const short8v*)&As[0][wr + fr * 16 + ln][g * 8];
            short8v a1 = *(const short8v*)&As[1][wr + fr * 16 + ln][g * 8];
            short8v a2 = *(const short8v*)&As[2][wr + fr * 16 + ln][g * 8];
#pragma unroll
            for (int fc = 0; fc < 4; ++fc) {
                f32x4 d = acc[fr][fc];
                d = __builtin_amdgcn_mfma_f32_16x16x32_bf16(a0, bfr[0][fc], d, 0, 0, 0);
                d = __builtin_amdgcn_mfma_f32_16x16x32_bf16(a0, bfr[1][fc], d, 0, 0, 0);
                d = __builtin_amdgcn_mfma_f32_16x16x32_bf16(a1, bfr[0][fc], d, 0, 0, 0);
                d = __builtin_amdgcn_mfma_f32_16x16x32_bf16(a0, bfr[2][fc], d, 0, 0, 0);
                d = __builtin_amdgcn_mfma_f32_16x16x32_bf16(a1, bfr[1][fc], d, 0, 0, 0);
                d = __builtin_amdgcn_mfma_f32_16x16x32_bf16(a2, bfr[0][fc], d, 0, 0, 0);
                acc[fr][fc] = d;
            }
        }
    }
    // C/D layout (m89): col = lane&15, row = (lane>>4)*4 + reg
    float* dst = part + (size_t)blockIdx.z * (1024 * 1024);
    int rbase = row0 + wr, cbase = col0 + wc;
#pragma unroll
    for (int fr = 0; fr < 4; ++fr)
#pragma unroll
        for (int fc = 0; fc < 4; ++fc)
#pragma unroll
            for (int reg = 0; reg < 4; ++reg)
                dst[(size_t)(rbase + fr * 16 + g * 4 + reg) * 1024 + cbase + fc * 16 + ln] =
                    acc[fr][fc][reg];
}

// ---------------- fp32 split-K GEMM (GEMM2, verified R3 path) ----------------
__global__ __launch_bounds__(256) void gemm_splitk(const float* __restrict__ A,
    const float* __restrict__ B, float* __restrict__ part,
    int Mdim, int Ndim, int Kdim, int Ks, int permute)
{
    __shared__ float As[32][68];
    __shared__ float Bs[32][128];
    int tid = threadIdx.x;
    int col0 = blockIdx.x * 128;
    int row0 = blockIdx.y * 64;
    int kOff = blockIdx.z * Ks;
    int ty = tid >> 4, tx = tid & 15;
    int ar0 = tid >> 3;
    int af  = tid & 7;
    int aswz = (af & 3) << 3;
    int bkr0 = tid >> 5;
    int bf   = tid & 31;
    float4 pa0, pa1, pb0, pb1, pb2, pb3;

    auto loadA = [&](int k0) {
        int gr0 = row0 + ar0;
        int gr1 = gr0 + 32;
        pa0 = make_float4(0.f, 0.f, 0.f, 0.f);
        pa1 = make_float4(0.f, 0.f, 0.f, 0.f);
        if (gr0 < Mdim) pa0 = *(const float4*)&A[(size_t)gr0 * Kdim + kOff + k0 + af * 4];
        if (gr1 < Mdim) pa1 = *(const float4*)&A[(size_t)gr1 * Kdim + kOff + k0 + af * 4];
    };
    auto rowB = [&](int k0, int i) {
        int kg = kOff + k0 + bkr0 + 8 * i;
        int brv = permute ? ((kg & 255) * 49 + (kg >> 8)) : kg;
        return (const float4*)&B[(size_t)brv * Ndim + col0 + bf * 4];
    };
    auto loadB = [&](int k0) {
        pb0 = *rowB(k0, 0);
        pb1 = *rowB(k0, 1);
        pb2 = *rowB(k0, 2);
        pb3 = *rowB(k0, 3);
    };
    auto store = [&]() {
        int rc0 = ar0 ^ aswz;
        int rc1 = (ar0 + 32) ^ aswz;
        As[af * 4 + 0][rc0] = pa0.x;
        As[af * 4 + 1][rc0] = pa0.y;
        As[af * 4 + 2][rc0] = pa0.z;
        As[af * 4 + 3][rc0] = pa0.w;
        As[af * 4 + 0][rc1] = pa1.x;
        As[af * 4 + 1][rc1] = pa1.y;
        As[af * 4 + 2][rc1] = pa1.z;
        As[af * 4 + 3][rc1] = pa1.w;
        *(float4*)&Bs[bkr0 +  0][bf * 4] = pb0;
        *(float4*)&Bs[bkr0 +  8][bf * 4] = pb1;
        *(float4*)&Bs[bkr0 + 16][bf * 4] = pb2;
        *(float4*)&Bs[bkr0 + 24][bf * 4] = pb3;
    };

    float acc[4][8] = {};
    loadA(0); loadB(0);
    for (int k0 = 0; k0 < Ks; k0 += 32) {
        __syncthreads();
        store();
        __syncthreads();
        if (k0 + 32 < Ks) { loadA(k0 + 32); loadB(k0 + 32); }
#pragma unroll 8
        for (int kk = 0; kk < 32; ++kk) {
            int sa = ((kk >> 2) & 3) << 3;
            float4 a  = *(const float4*)&As[kk][(ty * 4) ^ sa];
            float4 b0 = *(const float4*)&Bs[kk][tx * 4];
            float4 b1 = *(const float4*)&Bs[kk][64 + tx * 4];
            float ar[4] = {a.x, a.y, a.z, a.w};
            float br[8] = {b0.x, b0.y, b0.z, b0.w, b1.x, b1.y, b1.z, b1.w};
#pragma unroll
            for (int i2 = 0; i2 < 4; ++i2)
#pragma unroll
                for (int j = 0; j < 8; ++j)
                    acc[i2][j] += ar[i2] * br[j];
        }
    }
    float* dst = part + (size_t)blockIdx.z * Mdim * Ndim;
    int gcA = col0 + tx * 4, gcB = col0 + 64 + tx * 4;
#pragma unroll
    for (int i2 = 0; i2 < 4; ++i2) {
        int gr = row0 + ty * 4 + i2;
        if (gr < Mdim) {
            *(float4*)&dst[(size_t)gr * Ndim + gcA] =
                make_float4(acc[i2][0], acc[i2][1], acc[i2][2], acc[i2][3]);
            *(float4*)&dst[(size_t)gr * Ndim + gcB] =
                make_float4(acc[i2][4], acc[i2][5], acc[i2][6], acc[i2][7]);
        }
    }
}

// ---------------- split-K reduce + bias + relu ----------------
__global__ __launch_bounds__(256) void reduce_bias_relu_k(const float* __restrict__ part,
    const float* __restrict__ bias, float* __restrict__ outp, int Ndim, int S, int MN)
{
    int m = blockIdx.x, t = threadIdx.x;
    size_t o = (size_t)m * Ndim + t * 4;
    float4 acc = *(const float4*)&part[o];
    for (int s = 1; s < S; ++s) {
        float4 p = *(const float4*)&part[(size_t)s * MN + o];
        acc.x += p.x; acc.y += p.y; acc.z += p.z; acc.w += p.w;
    }
    float4 bv = *(const float4*)&bias[t * 4];
    acc.x = fmaxf(acc.x + bv.x, 0.f);
    acc.y = fmaxf(acc.y + bv.y, 0.f);
    acc.z = fmaxf(acc.z + bv.z, 0.f);
    acc.w = fmaxf(acc.w + bv.w, 0.f);
    *(float4*)&outp[o] = acc;
}

// ---------------- cls/box heads ----------------
__global__ __launch_bounds__(128) void heads_k(const float* __restrict__ h,
    const float* __restrict__ w_cls, const float* __restrict__ b_cls,
    const float* __restrict__ w_box, const float* __restrict__ b_box,
    float* __restrict__ logits, float* __restrict__ deltas)
{
    __shared__ float sh[1024];
    int n = blockIdx.x;
    for (int i = threadIdx.x; i < 1024; i += 128) sh[i] = h[(size_t)n * 1024 + i];
    __syncthreads();
    int j = threadIdx.x;
    if (j < 21) {
        float acc = b_cls[j];
        for (int k = 0; k < 1024; ++k) acc += sh[k] * w_cls[k * 21 + j];
        logits[n * 21 + j] = acc;
    } else if (j < 105) {
        int jj = j - 21;
        float acc = b_box[jj];
        for (int k = 0; k < 1024; ++k) acc += sh[k] * w_box[k * 84 + jj];
        deltas[n * 84 + jj] = acc;
    }
}

// ---------------- softmax + decode + clip + mask ----------------
__global__ __launch_bounds__(64) void postproc_k(const float* __restrict__ logits,
    const float* __restrict__ deltas, const float* __restrict__ prop,
    const int* __restrict__ img_h_p, const int* __restrict__ img_w_p,
    float* __restrict__ scores_m, float* __restrict__ boxes_dec)
{
    int n = blockIdx.x;
    int cls = threadIdx.x;
    if (cls < 1 || cls > 20) return;
    float mx = -3.0e38f;
    for (int i = 0; i < 21; ++i) mx = fmaxf(mx, logits[n * 21 + i]);
    float sum = 0.f;
    for (int i = 0; i < 21; ++i) sum += expf(logits[n * 21 + i] - mx);
    float score = expf(logits[n * 21 + cls] - mx) / sum;

    float p0 = prop[n * 4 + 0], p1 = prop[n * 4 + 1];
    float p2 = prop[n * 4 + 2], p3 = prop[n * 4 + 3];
    float w = p2 - p0, h = p3 - p1;
    float cx = p0 + 0.5f * w, cy = p1 + 0.5f * h;
    float d0 = deltas[n * 84 + cls * 4 + 0];
    float d1 = deltas[n * 84 + cls * 4 + 1];
    float d2 = deltas[n * 84 + cls * 4 + 2];
    float d3 = deltas[n * 84 + cls * 4 + 3];
    const float CLIP = 4.135166556742356f;  // log(1000/16)
    float dx = d0 / 10.0f, dy = d1 / 10.0f;
    float dw = fminf(d2 / 5.0f, CLIP), dh = fminf(d3 / 5.0f, CLIP);
    float pcx = dx * w + cx, pcy = dy * h + cy;
    float pw = expf(dw) * w, ph = expf(dh) * h;
    float bx1 = pcx - 0.5f * pw, by1 = pcy - 0.5f * ph;
    float bx2 = pcx + 0.5f * pw, by2 = pcy + 0.5f * ph;
    float iw = (float)img_w_p[0], ih = (float)img_h_p[0];
    bx1 = fminf(fmaxf(bx1, 0.f), iw);
    by1 = fminf(fmaxf(by1, 0.f), ih);
    bx2 = fminf(fmaxf(bx2, 0.f), iw);
    by2 = fminf(fmaxf(by2, 0.f), ih);
    float bw = bx2 - bx1, bh = by2 - by1;
    bool keep = (bw >= 1.0f) && (bh >= 1.0f) && (score >= 0.05f);
    int o = (cls - 1) * 1000 + n;
    scores_m[o] = keep ? score : NEGV;
    ((float4*)boxes_dec)[o] = make_float4(bx1, by1, bx2, by2);
}

// ---------------- per-class NMS (exact JAX scan semantics) ----------------
__global__ __launch_bounds__(1024) void nms_k(const float* __restrict__ scores_m,
    const float* __restrict__ boxes_dec, float* __restrict__ out)
{
    int cls = blockIdx.x;
    int t = threadIdx.x;
    __shared__ float s[1000];
    __shared__ float4 bx[1000];
    __shared__ unsigned long long red[16];
    __shared__ float4 selb_s;
    __shared__ int seli_s;
    __shared__ int done_s;
    if (t < 1000) {
        s[t] = scores_m[cls * 1000 + t];
        bx[t] = ((const float4*)boxes_dec)[cls * 1000 + t];
    }
    float* kb  = out;
    float* ksc = out + 8000;
    float* klab = out + 10000;
    if (t < 100) klab[cls * 100 + t] = (float)(cls + 1);
    if (t == 0) done_s = 0;
    __syncthreads();
    for (int it = 0; it < 100; ++it) {
        float v = (t < 1000) ? s[t] : -3.0e38f;
        unsigned ub = __float_as_uint(v);
        ub = (ub & 0x80000000u) ? ~ub : (ub | 0x80000000u);
        unsigned long long key = ((unsigned long long)ub << 32) | (unsigned)(1023 - t);
#pragma unroll
        for (int off = 1; off < 64; off <<= 1) {
            unsigned long long o = __shfl_xor(key, off, 64);
            key = (o > key) ? o : key;
        }
        if ((t & 63) == 0) red[t >> 6] = key;
        __syncthreads();
        if (t == 0) {
            unsigned long long best = red[0];
            for (int i = 1; i < 16; ++i) if (red[i] > best) best = red[i];
            int idx = 1023 - (int)(best & 0xFFFFFFFFu);
            float bv = s[idx];
            seli_s = idx;
            selb_s = bx[idx];
            if (bv <= 0.5f * NEGV) {
                done_s = 1;
            } else {
                ((float4*)kb)[cls * 100 + it] = bx[idx];
                ksc[cls * 100 + it] = bv;
            }
        }
        __syncthreads();
        if (done_s) {
            for (int k = it + t; k < 100; k += 1024) {
                ((float4*)kb)[cls * 100 + k] = make_float4(0.f, 0.f, 0.f, 0.f);
                ksc[cls * 100 + k] = 0.0f;
            }
            break;
        }
        if (t < 1000) {
            float4 b = selb_s;
            float4 c = bx[t];
            float ltx = fmaxf(b.x, c.x), lty = fmaxf(b.y, c.y);
            float rbx = fminf(b.z, c.z), rby = fminf(b.w, c.w);
            float wiw = fmaxf(rbx - ltx, 0.0f), wih = fmaxf(rby - lty, 0.0f);
            float inter = wiw * wih;
            float a1 = (b.z - b.x) * (b.w - b.y);
            float a2 = (c.z - c.x) * (c.w - c.y);
            float iou = inter / (a1 + a2 - inter + 1e-9f);
            if (iou > 0.5f || t == seli_s) s[t] = NEGV;
        }
        __syncthreads();
    }
}

extern "C" void kernel_launch(void* const* d_in, const int* in_sizes, int n_in,
                              void* d_out, int out_size, void* d_ws, size_t ws_size,
                              hipStream_t stream)
{
    const float* feat  = (const float*)d_in[0];
    const float* prop  = (const float*)d_in[1];
    const float* w1    = (const float*)d_in[2];
    const float* b1    = (const float*)d_in[3];
    const float* w2    = (const float*)d_in[4];
    const float* b2    = (const float*)d_in[5];
    const float* w_cls = (const float*)d_in[6];
    const float* b_cls = (const float*)d_in[7];
    const float* w_box = (const float*)d_in[8];
    const float* b_box = (const float*)d_in[9];
    const int* img_h   = (const int*)d_in[10];
    const int* img_w   = (const int*)d_in[11];

    char* wsb = (char*)d_ws;
    unsigned short* Apl = (unsigned short*)wsb;                    // 3 planes: 77,070,336 B
    unsigned short* Bpl = (unsigned short*)(wsb + 77070336);       // 3 planes: 77,070,336 B
    float* part   = (float*)(wsb + 154140672);                     // 8*1024*1024*4 = 33,554,432 B
    float* h1     = (float*)(wsb + 187695104);                     // 4,096,000 B
    float* h2     = (float*)(wsb + 191791104);                     // 4,096,000 B
    float* logits = (float*)(wsb + 195887104);                     // 84,000 B
    float* deltas = (float*)(wsb + 195971104);                     // 336,000 B
    float* scores_m  = (float*)(wsb + 196307104);                  // 80,000 B
    float* boxes_dec = (float*)(wsb + 196387104);                  // 320,000 B
    float* outp = (float*)d_out;

    hipLaunchKernelGGL(roi_align_split3, dim3(49, 1000), dim3(256), 0, stream,
                       feat, prop, Apl);
    hipLaunchKernelGGL(zero_padA, dim3(441), dim3(256), 0, stream, Apl);
    hipLaunchKernelGGL(conv_w1_k, dim3(196, 16), dim3(256), 0, stream, w1, Bpl);
    hipLaunchKernelGGL(gemm_mfma_split3, dim3(8, 8, 8), dim3(256), 0, stream,
                       Apl, Bpl, part, 1568);
    hipLaunchKernelGGL(reduce_bias_relu_k, dim3(1000), dim3(256), 0, stream,
                       part, b1, h1, 1024, 8, 1024 * 1024);
    hipLaunchKernelGGL(gemm_splitk, dim3(8, 16, 4), dim3(256), 0, stream,
                       h1, w2, part, 1000, 1024, 1024, 256, 0);
    hipLaunchKernelGGL(reduce_bias_relu_k, dim3(1000), dim3(256), 0, stream,
                       part, b2, h2, 1024, 4, 1024000);
    hipLaunchKernelGGL(heads_k, dim3(1000), dim3(128), 0, stream,
                       h2, w_cls, b_cls, w_box, b_box, logits, deltas);
    hipLaunchKernelGGL(postproc_k, dim3(1000), dim3(64), 0, stream,
                       logits, deltas, prop, img_h, img_w, scores_m, boxes_dec);
    hipLaunchKernelGGL(nms_k, dim3(20), dim3(1024), 0, stream, scores_m, boxes_dec, outp);
}

// Round 5
// 617.378 us; speedup vs baseline: 1.5457x; 1.5457x over previous
//
#include <hip/hip_runtime.h>

// RoIHeads pipeline: roi_align -> FC1(relu) -> FC2(relu) -> cls/box heads ->
// softmax/decode/clip/mask -> per-class NMS.
//
// R5 (from R4 rocprof: WRITE_SIZE 1.19GB = scratch spills; FETCH 871MB = 8x
// cross-XCD panel re-reads; MfmaUtil 12.6%):
//  - gemm_mfma_split3 rewritten: global_load_lds (zero staging VGPRs), linear
//    [128][32] LDS tiles (conflict-free b128), low-pressure inner loop,
//    XCD cluster swizzle (4col x 2row per XCD) -> A 2x, B 4x re-reads.
//  - nms_k rewritten single-wave (64 lanes x 16 boxes in VGPRs, no barriers).

#define NEGV -1000000000.0f

typedef __attribute__((ext_vector_type(8))) short short8v;  // 8 bf16 (4 VGPR)
typedef __attribute__((ext_vector_type(4))) float f32x4;

#define KDIM 12544
#define PL   (1024 * 12544)   // plane elems (1024 padded rows)

__device__ __forceinline__ unsigned short to_bf16(float f) {
    unsigned u = __float_as_uint(f);
    unsigned r = u + 0x7FFFu + ((u >> 16) & 1u);   // RNE
    return (unsigned short)(r >> 16);
}
__device__ __forceinline__ float bf2f(unsigned short s) {
    return __uint_as_float((unsigned)s << 16);
}
__device__ __forceinline__ void gload16(const void* gsrc, void* ldst) {
    __builtin_amdgcn_global_load_lds(
        (const __attribute__((address_space(1))) unsigned int*)gsrc,
        (__attribute__((address_space(3))) unsigned int*)ldst,
        16, 0, 0);
}

// ---------------- RoI align + 3-way bf16 split ----------------
__global__ __launch_bounds__(256) void roi_align_split3(const float* __restrict__ feat,
    const float* __restrict__ prop, unsigned short* __restrict__ Ap)
{
    int n = blockIdx.y;
    int p = blockIdx.x;
    int my = p / 7, mx = p % 7;
    float x1 = prop[n * 4 + 0] * 0.0625f;
    float y1 = prop[n * 4 + 1] * 0.0625f;
    float x2 = prop[n * 4 + 2] * 0.0625f;
    float y2 = prop[n * 4 + 3] * 0.0625f;
    float rw = fmaxf(x2 - x1, 1.0f), rh = fmaxf(y2 - y1, 1.0f);
    float y = y1 + ((float)my + 0.5f) * (rh / 7.0f);
    float x = x1 + ((float)mx + 0.5f) * (rw / 7.0f);
    bool oob = (y < -1.0f) || (y > 50.0f) || (x < -1.0f) || (x > 50.0f);
    y = fminf(fmaxf(y, 0.0f), 49.0f);
    x = fminf(fmaxf(x, 0.0f), 49.0f);
    int y0 = (int)floorf(y), x0 = (int)floorf(x);
    int y1i = min(y0 + 1, 49), x1i = min(x0 + 1, 49);
    float ly = y - (float)y0, lx = x - (float)x0;
    float hy = 1.0f - ly, hx = 1.0f - lx;
    int c = threadIdx.x;
    float v = feat[(y0 * 50 + x0) * 256 + c] * (hy * hx)
            + feat[(y0 * 50 + x1i) * 256 + c] * (hy * lx)
            + feat[(y1i * 50 + x0) * 256 + c] * (ly * hx)
            + feat[(y1i * 50 + x1i) * 256 + c] * (ly * lx);
    if (oob) v = 0.0f;
    unsigned short s1 = to_bf16(v);  float r  = v - bf2f(s1);
    unsigned short s2 = to_bf16(r);  float r2 = r - bf2f(s2);
    unsigned short s3 = to_bf16(r2);
    size_t o = (size_t)n * KDIM + p * 256 + c;
    Ap[o] = s1; Ap[PL + o] = s2; Ap[2 * (size_t)PL + o] = s3;
}

// zero rows 1000..1023 of the 3 A-planes
__global__ __launch_bounds__(256) void zero_padA(unsigned short* __restrict__ Ap)
{
    int id = blockIdx.x * 256 + threadIdx.x;     // < 3*24*1568
    int p = id / 37632;
    int rem = id - p * 37632;
    int r = rem / 1568, c8 = rem - r * 1568;
    *(uint4*)&Ap[(size_t)p * PL + (size_t)(1000 + r) * KDIM + c8 * 8] =
        make_uint4(0, 0, 0, 0);
}

// ---------------- w1 -> 3 bf16 planes, permuted + transposed ----------------
__global__ __launch_bounds__(256) void conv_w1_k(const float* __restrict__ w1,
    unsigned short* __restrict__ Bt)
{
    __shared__ unsigned short T[3][64][72];
    int k0 = blockIdx.x * 64;
    int n0 = blockIdx.y * 64;
    int t = threadIdx.x;
#pragma unroll
    for (int j = 0; j < 16; ++j) {
        int idx = t + 256 * j;
        int n_l = idx & 63, k_l = idx >> 6;
        int kp = k0 + k_l;
        int orow = (kp & 255) * 49 + (kp >> 8);
        float v = w1[(size_t)orow * 1024 + n0 + n_l];
        unsigned short s1 = to_bf16(v);  float r  = v - bf2f(s1);
        unsigned short s2 = to_bf16(r);  float r2 = r - bf2f(s2);
        T[0][k_l][n_l] = s1;
        T[1][k_l][n_l] = s2;
        T[2][k_l][n_l] = to_bf16(r2);
    }
    __syncthreads();
#pragma unroll
    for (int p = 0; p < 3; ++p)
#pragma unroll
        for (int jj = 0; jj < 2; ++jj) {
            int w = t + 256 * jj;
            int n_l = w >> 3, kg = w & 7;
            short8v pk;
#pragma unroll
            for (int e = 0; e < 8; ++e) pk[e] = (short)T[p][kg * 8 + e][n_l];
            *(short8v*)&Bt[(size_t)p * PL + (size_t)(n0 + n_l) * KDIM + k0 + kg * 8] = pk;
        }
}

// ---------------- split-3 bf16 MFMA GEMM (GEMM1) ----------------
// 512 blocks 1D, decode -> (col, row, z) with XCD cluster swizzle.
// BM=BN=128, BK=32, 4 waves (2x2 of 64x64), LDS linear [plane][128][32] bf16,
// staged via global_load_lds (no staging VGPRs). part[z][1024][1024].
__global__ __launch_bounds__(256, 3) void gemm_mfma_split3(
    const unsigned short* __restrict__ Ap, const unsigned short* __restrict__ Bp,
    float* __restrict__ part, int Ks)
{
    __shared__ unsigned short ldsb[24576];   // 48 KB: A 3x128x32 | B 3x128x32

    // --- XCD cluster swizzle: cluster = 4 cols x 2 rows, b%8 == cluster%8 ---
    int b = blockIdx.x;
    int xcd = b & 7;
    int rest = b >> 3;
    int m = rest & 7;           // member in cluster
    int qhi = rest >> 3;
    int q = xcd + 8 * qhi;      // cluster 0..63
    int z  = q >> 3;
    int qz = q & 7;
    int col0 = ((qz & 1) * 4 + (m & 3)) * 128;
    int row0 = ((qz >> 1) * 2 + (m >> 2)) * 128;
    int kOff = z * Ks;

    int t = threadIdx.x;
    int w = t >> 6;
    int lane = t & 63;
    int ln = lane & 15, g = lane >> 4;
    int wr = (w >> 1) * 64, wc = (w & 1) * 64;

    // staging role: waves 0-1 stage A (24 instrs), waves 2-3 stage B
    const unsigned short* smat = (w >= 2) ? Bp : Ap;
    int sbase = (w >= 2) ? col0 : row0;
    char* lbase = (char*)ldsb + ((w >= 2) ? 12288 * 2 : 0);
    int j0 = (w & 1) * 12;
    int srow_lane = lane >> 2;          // row within 16-row block
    int scol_lane = (lane & 3) * 8;     // k elems

    f32x4 acc[4][4] = {};
    const unsigned short* lds_us = ldsb;

    int nks = Ks >> 5;
    for (int ks = 0; ks < nks; ++ks) {
        int kpos = kOff + (ks << 5) + scol_lane;
        // ---- stage tile (12 x global_load_lds per wave) ----
#pragma unroll
        for (int ii = 0; ii < 12; ++ii) {
            int j = j0 + ii;            // 0..23 within this matrix
            int p = j >> 3, rb = j & 7;
            const unsigned short* src = smat + (size_t)p * PL
                + (size_t)(sbase + rb * 16 + srow_lane) * KDIM + kpos;
            gload16(src, lbase + p * 8192 + rb * 1024);
        }
        __syncthreads();                // vmcnt(0) drain -> tile ready
        // ---- compute: 6 plane-pair products ----
#pragma unroll
        for (int pb = 0; pb < 3; ++pb) {
            short8v bf[4];
#pragma unroll
            for (int fc = 0; fc < 4; ++fc)
                bf[fc] = *(const short8v*)&lds_us[12288 + pb * 4096 + (wc + fc * 16 + ln) * 32 + g * 8];
#pragma unroll
            for (int pa = 0; pa < 3; ++pa) {
                if (pa + pb >= 3) break;
                short8v af[4];
#pragma unroll
                for (int fr = 0; fr < 4; ++fr)
                    af[fr] = *(const short8v*)&lds_us[pa * 4096 + (wr + fr * 16 + ln) * 32 + g * 8];
#pragma unroll
                for (int fr = 0; fr < 4; ++fr)
#pragma unroll
                    for (int fc = 0; fc < 4; ++fc)
                        acc[fr][fc] = __builtin_amdgcn_mfma_f32_16x16x32_bf16(
                            af[fr], bf[fc], acc[fr][fc], 0, 0, 0);
            }
        }
        __syncthreads();                // all reads done before next overwrite
    }
    // C/D layout: col = lane&15, row = (lane>>4)*4 + reg
    float* dst = part + (size_t)z * (1024 * 1024);
    int rbase = row0 + wr, cbase = col0 + wc;
#pragma unroll
    for (int fr = 0; fr < 4; ++fr)
#pragma unroll
        for (int fc = 0; fc < 4; ++fc)
#pragma unroll
            for (int reg = 0; reg < 4; ++reg)
                dst[(size_t)(rbase + fr * 16 + g * 4 + reg) * 1024 + cbase + fc * 16 + ln] =
                    acc[fr][fc][reg];
}

// ---------------- fp32 split-K GEMM (GEMM2, verified R3 path) ----------------
__global__ __launch_bounds__(256) void gemm_splitk(const float* __restrict__ A,
    const float* __restrict__ B, float* __restrict__ part,
    int Mdim, int Ndim, int Kdim, int Ks, int permute)
{
    __shared__ float As[32][68];
    __shared__ float Bs[32][128];
    int tid = threadIdx.x;
    int col0 = blockIdx.x * 128;
    int row0 = blockIdx.y * 64;
    int kOff = blockIdx.z * Ks;
    int ty = tid >> 4, tx = tid & 15;
    int ar0 = tid >> 3;
    int af  = tid & 7;
    int aswz = (af & 3) << 3;
    int bkr0 = tid >> 5;
    int bf   = tid & 31;
    float4 pa0, pa1, pb0, pb1, pb2, pb3;

    auto loadA = [&](int k0) {
        int gr0 = row0 + ar0;
        int gr1 = gr0 + 32;
        pa0 = make_float4(0.f, 0.f, 0.f, 0.f);
        pa1 = make_float4(0.f, 0.f, 0.f, 0.f);
        if (gr0 < Mdim) pa0 = *(const float4*)&A[(size_t)gr0 * Kdim + kOff + k0 + af * 4];
        if (gr1 < Mdim) pa1 = *(const float4*)&A[(size_t)gr1 * Kdim + kOff + k0 + af * 4];
    };
    auto rowB = [&](int k0, int i) {
        int kg = kOff + k0 + bkr0 + 8 * i;
        int brv = permute ? ((kg & 255) * 49 + (kg >> 8)) : kg;
        return (const float4*)&B[(size_t)brv * Ndim + col0 + bf * 4];
    };
    auto loadB = [&](int k0) {
        pb0 = *rowB(k0, 0);
        pb1 = *rowB(k0, 1);
        pb2 = *rowB(k0, 2);
        pb3 = *rowB(k0, 3);
    };
    auto store = [&]() {
        int rc0 = ar0 ^ aswz;
        int rc1 = (ar0 + 32) ^ aswz;
        As[af * 4 + 0][rc0] = pa0.x;
        As[af * 4 + 1][rc0] = pa0.y;
        As[af * 4 + 2][rc0] = pa0.z;
        As[af * 4 + 3][rc0] = pa0.w;
        As[af * 4 + 0][rc1] = pa1.x;
        As[af * 4 + 1][rc1] = pa1.y;
        As[af * 4 + 2][rc1] = pa1.z;
        As[af * 4 + 3][rc1] = pa1.w;
        *(float4*)&Bs[bkr0 +  0][bf * 4] = pb0;
        *(float4*)&Bs[bkr0 +  8][bf * 4] = pb1;
        *(float4*)&Bs[bkr0 + 16][bf * 4] = pb2;
        *(float4*)&Bs[bkr0 + 24][bf * 4] = pb3;
    };

    float acc[4][8] = {};
    loadA(0); loadB(0);
    for (int k0 = 0; k0 < Ks; k0 += 32) {
        __syncthreads();
        store();
        __syncthreads();
        if (k0 + 32 < Ks) { loadA(k0 + 32); loadB(k0 + 32); }
#pragma unroll 8
        for (int kk = 0; kk < 32; ++kk) {
            int sa = ((kk >> 2) & 3) << 3;
            float4 a  = *(const float4*)&As[kk][(ty * 4) ^ sa];
            float4 b0 = *(const float4*)&Bs[kk][tx * 4];
            float4 b1 = *(const float4*)&Bs[kk][64 + tx * 4];
            float ar[4] = {a.x, a.y, a.z, a.w};
            float br[8] = {b0.x, b0.y, b0.z, b0.w, b1.x, b1.y, b1.z, b1.w};
#pragma unroll
            for (int i2 = 0; i2 < 4; ++i2)
#pragma unroll
                for (int j = 0; j < 8; ++j)
                    acc[i2][j] += ar[i2] * br[j];
        }
    }
    float* dst = part + (size_t)blockIdx.z * Mdim * Ndim;
    int gcA = col0 + tx * 4, gcB = col0 + 64 + tx * 4;
#pragma unroll
    for (int i2 = 0; i2 < 4; ++i2) {
        int gr = row0 + ty * 4 + i2;
        if (gr < Mdim) {
            *(float4*)&dst[(size_t)gr * Ndim + gcA] =
                make_float4(acc[i2][0], acc[i2][1], acc[i2][2], acc[i2][3]);
            *(float4*)&dst[(size_t)gr * Ndim + gcB] =
                make_float4(acc[i2][4], acc[i2][5], acc[i2][6], acc[i2][7]);
        }
    }
}

// ---------------- split-K reduce + bias + relu ----------------
__global__ __launch_bounds__(256) void reduce_bias_relu_k(const float* __restrict__ part,
    const float* __restrict__ bias, float* __restrict__ outp, int Ndim, int S, int MN)
{
    int m = blockIdx.x, t = threadIdx.x;
    size_t o = (size_t)m * Ndim + t * 4;
    float4 acc = *(const float4*)&part[o];
    for (int s = 1; s < S; ++s) {
        float4 p = *(const float4*)&part[(size_t)s * MN + o];
        acc.x += p.x; acc.y += p.y; acc.z += p.z; acc.w += p.w;
    }
    float4 bv = *(const float4*)&bias[t * 4];
    acc.x = fmaxf(acc.x + bv.x, 0.f);
    acc.y = fmaxf(acc.y + bv.y, 0.f);
    acc.z = fmaxf(acc.z + bv.z, 0.f);
    acc.w = fmaxf(acc.w + bv.w, 0.f);
    *(float4*)&outp[o] = acc;
}

// ---------------- cls/box heads ----------------
__global__ __launch_bounds__(128) void heads_k(const float* __restrict__ h,
    const float* __restrict__ w_cls, const float* __restrict__ b_cls,
    const float* __restrict__ w_box, const float* __restrict__ b_box,
    float* __restrict__ logits, float* __restrict__ deltas)
{
    __shared__ float sh[1024];
    int n = blockIdx.x;
    for (int i = threadIdx.x; i < 1024; i += 128) sh[i] = h[(size_t)n * 1024 + i];
    __syncthreads();
    int j = threadIdx.x;
    if (j < 21) {
        float acc = b_cls[j];
        for (int k = 0; k < 1024; ++k) acc += sh[k] * w_cls[k * 21 + j];
        logits[n * 21 + j] = acc;
    } else if (j < 105) {
        int jj = j - 21;
        float acc = b_box[jj];
        for (int k = 0; k < 1024; ++k) acc += sh[k] * w_box[k * 84 + jj];
        deltas[n * 84 + jj] = acc;
    }
}

// ---------------- softmax + decode + clip + mask ----------------
__global__ __launch_bounds__(64) void postproc_k(const float* __restrict__ logits,
    const float* __restrict__ deltas, const float* __restrict__ prop,
    const int* __restrict__ img_h_p, const int* __restrict__ img_w_p,
    float* __restrict__ scores_m, float* __restrict__ boxes_dec)
{
    int n = blockIdx.x;
    int cls = threadIdx.x;
    if (cls < 1 || cls > 20) return;
    float mx = -3.0e38f;
    for (int i = 0; i < 21; ++i) mx = fmaxf(mx, logits[n * 21 + i]);
    float sum = 0.f;
    for (int i = 0; i < 21; ++i) sum += expf(logits[n * 21 + i] - mx);
    float score = expf(logits[n * 21 + cls] - mx) / sum;

    float p0 = prop[n * 4 + 0], p1 = prop[n * 4 + 1];
    float p2 = prop[n * 4 + 2], p3 = prop[n * 4 + 3];
    float w = p2 - p0, h = p3 - p1;
    float cx = p0 + 0.5f * w, cy = p1 + 0.5f * h;
    float d0 = deltas[n * 84 + cls * 4 + 0];
    float d1 = deltas[n * 84 + cls * 4 + 1];
    float d2 = deltas[n * 84 + cls * 4 + 2];
    float d3 = deltas[n * 84 + cls * 4 + 3];
    const float CLIP = 4.135166556742356f;  // log(1000/16)
    float dx = d0 / 10.0f, dy = d1 / 10.0f;
    float dw = fminf(d2 / 5.0f, CLIP), dh = fminf(d3 / 5.0f, CLIP);
    float pcx = dx * w + cx, pcy = dy * h + cy;
    float pw = expf(dw) * w, ph = expf(dh) * h;
    float bx1 = pcx - 0.5f * pw, by1 = pcy - 0.5f * ph;
    float bx2 = pcx + 0.5f * pw, by2 = pcy + 0.5f * ph;
    float iw = (float)img_w_p[0], ih = (float)img_h_p[0];
    bx1 = fminf(fmaxf(bx1, 0.f), iw);
    by1 = fminf(fmaxf(by1, 0.f), ih);
    bx2 = fminf(fmaxf(bx2, 0.f), iw);
    by2 = fminf(fmaxf(by2, 0.f), ih);
    float bw = bx2 - bx1, bh = by2 - by1;
    bool keep = (bw >= 1.0f) && (bh >= 1.0f) && (score >= 0.05f);
    int o = (cls - 1) * 1000 + n;
    scores_m[o] = keep ? score : NEGV;
    ((float4*)boxes_dec)[o] = make_float4(bx1, by1, bx2, by2);
}

// ---------------- per-class NMS: single wave, registers only ----------------
// grid = 20 blocks x 64 thr. 16 boxes/lane in VGPRs; shuffle argmax
// (first-index tiebreak), no barriers. Exact JAX scan semantics.
__global__ __launch_bounds__(64) void nms_k(const float* __restrict__ scores_m,
    const float* __restrict__ boxes_dec, float* __restrict__ out)
{
    int cls = blockIdx.x;
    int lane = threadIdx.x;
    float sc[16];
    float4 bx[16];
#pragma unroll
    for (int j = 0; j < 16; ++j) {
        int idx = j * 64 + lane;
        if (idx < 1000) {
            sc[j] = scores_m[cls * 1000 + idx];
            bx[j] = ((const float4*)boxes_dec)[cls * 1000 + idx];
        } else {
            sc[j] = -3.0e38f;
            bx[j] = make_float4(0.f, 0.f, 0.f, 0.f);
        }
    }
    float* kb   = out;            // [2000][4]
    float* ksc  = out + 8000;     // [2000]
    float* klab = out + 10000;    // [2000]
    for (int k2 = lane; k2 < 100; k2 += 64) klab[cls * 100 + k2] = (float)(cls + 1);

    int it = 0;
    for (; it < 100; ++it) {
        unsigned long long key = 0;
#pragma unroll
        for (int j = 0; j < 16; ++j) {
            unsigned ub = __float_as_uint(sc[j]);
            ub = (ub & 0x80000000u) ? ~ub : (ub | 0x80000000u);
            unsigned long long k2 = ((unsigned long long)ub << 32)
                                  | (unsigned)(1023 - (j * 64 + lane));
            key = (k2 > key) ? k2 : key;
        }
#pragma unroll
        for (int off = 1; off < 64; off <<= 1) {
            unsigned long long o = __shfl_xor(key, off, 64);
            key = (o > key) ? o : key;
        }
        unsigned ub2 = (unsigned)(key >> 32);
        unsigned uorig = (ub2 & 0x80000000u) ? (ub2 & 0x7FFFFFFFu) : ~ub2;
        float bv = __uint_as_float(uorig);
        if (bv <= 0.5f * NEGV) break;       // remaining slots -> zeros below

        int selIdx = 1023 - (int)(key & 0xFFFFFFFFu);
        int ownerLane = selIdx & 63;
        int slot = selIdx >> 6;             // wave-uniform
        float bxx = 0.f, bxy = 0.f, bxz = 0.f, bxw = 0.f;
#pragma unroll
        for (int j = 0; j < 16; ++j)
            if (j == slot) { bxx = bx[j].x; bxy = bx[j].y; bxz = bx[j].z; bxw = bx[j].w; }
        float4 sb;
        sb.x = __shfl(bxx, ownerLane, 64);
        sb.y = __shfl(bxy, ownerLane, 64);
        sb.z = __shfl(bxz, ownerLane, 64);
        sb.w = __shfl(bxw, ownerLane, 64);
        if (lane == 0) {
            ((float4*)kb)[cls * 100 + it] = sb;
            ksc[cls * 100 + it] = bv;
        }
        float a1 = (sb.z - sb.x) * (sb.w - sb.y);
#pragma unroll
        for (int j = 0; j < 16; ++j) {
            float ltx = fmaxf(sb.x, bx[j].x), lty = fmaxf(sb.y, bx[j].y);
            float rbx = fminf(sb.z, bx[j].z), rby = fminf(sb.w, bx[j].w);
            float wiw = fmaxf(rbx - ltx, 0.f), wih = fmaxf(rby - lty, 0.f);
            float inter = wiw * wih;
            float a2 = (bx[j].z - bx[j].x) * (bx[j].w - bx[j].y);
            float iou = inter / (a1 + a2 - inter + 1e-9f);
            if (iou > 0.5f || (j * 64 + lane) == selIdx) sc[j] = NEGV;
        }
    }
    for (int k2 = it + lane; k2 < 100; k2 += 64) {
        ((float4*)kb)[cls * 100 + k2] = make_float4(0.f, 0.f, 0.f, 0.f);
        ksc[cls * 100 + k2] = 0.0f;
    }
}

extern "C" void kernel_launch(void* const* d_in, const int* in_sizes, int n_in,
                              void* d_out, int out_size, void* d_ws, size_t ws_size,
                              hipStream_t stream)
{
    const float* feat  = (const float*)d_in[0];
    const float* prop  = (const float*)d_in[1];
    const float* w1    = (const float*)d_in[2];
    const float* b1    = (const float*)d_in[3];
    const float* w2    = (const float*)d_in[4];
    const float* b2    = (const float*)d_in[5];
    const float* w_cls = (const float*)d_in[6];
    const float* b_cls = (const float*)d_in[7];
    const float* w_box = (const float*)d_in[8];
    const float* b_box = (const float*)d_in[9];
    const int* img_h   = (const int*)d_in[10];
    const int* img_w   = (const int*)d_in[11];

    char* wsb = (char*)d_ws;
    unsigned short* Apl = (unsigned short*)wsb;                    // 77,070,336 B
    unsigned short* Bpl = (unsigned short*)(wsb + 77070336);       // 77,070,336 B
    float* part   = (float*)(wsb + 154140672);                     // 33,554,432 B
    float* h1     = (float*)(wsb + 187695104);
    float* h2     = (float*)(wsb + 191791104);
    float* logits = (float*)(wsb + 195887104);
    float* deltas = (float*)(wsb + 195971104);
    float* scores_m  = (float*)(wsb + 196307104);
    float* boxes_dec = (float*)(wsb + 196387104);
    float* outp = (float*)d_out;

    hipLaunchKernelGGL(roi_align_split3, dim3(49, 1000), dim3(256), 0, stream,
                       feat, prop, Apl);
    hipLaunchKernelGGL(zero_padA, dim3(441), dim3(256), 0, stream, Apl);
    hipLaunchKernelGGL(conv_w1_k, dim3(196, 16), dim3(256), 0, stream, w1, Bpl);
    hipLaunchKernelGGL(gemm_mfma_split3, dim3(512), dim3(256), 0, stream,
                       Apl, Bpl, part, 1568);
    hipLaunchKernelGGL(reduce_bias_relu_k, dim3(1000), dim3(256), 0, stream,
                       part, b1, h1, 1024, 8, 1024 * 1024);
    hipLaunchKernelGGL(gemm_splitk, dim3(8, 16, 4), dim3(256), 0, stream,
                       h1, w2, part, 1000, 1024, 1024, 256, 0);
    hipLaunchKernelGGL(reduce_bias_relu_k, dim3(1000), dim3(256), 0, stream,
                       part, b2, h2, 1024, 4, 1024000);
    hipLaunchKernelGGL(heads_k, dim3(1000), dim3(128), 0, stream,
                       h2, w_cls, b_cls, w_box, b_box, logits, deltas);
    hipLaunchKernelGGL(postproc_k, dim3(1000), dim3(64), 0, stream,
                       logits, deltas, prop, img_h, img_w, scores_m, boxes_dec);
    hipLaunchKernelGGL(nms_k, dim3(20), dim3(64), 0, stream, scores_m, boxes_dec, outp);
}

// Round 6
// 514.590 us; speedup vs baseline: 1.8545x; 1.1997x over previous
//
#include <hip/hip_runtime.h>

// RoIHeads pipeline: roi_align -> FC1(relu) -> FC2(relu) -> cls/box heads ->
// softmax/decode/clip/mask -> per-class NMS.
//
// R6 (from R5 rocprof: nms_k 181us top kernel, VALUBusy 1%, latency-bound
// serial scan): NMS re-architected as sort + IoU-bitmask + fast sweep.
//   scan(argmax/suppress) == greedy NMS over (score desc, idx asc) sorted
//   list (exact, incl. first-index tie-break via the same u64 keys).
//   sort: 20 blk bitonic (LDS). mask: 320 blk, 20x1000x1000 IoUs, bitset
//   rows (16 u64). sweep: 20 waves, 1000 steps x ~20cyc: ballot bit-check,
//   lane-sliced "suppr |= maskrow" (lane w owns word w -> local OR).
// GEMM path unchanged from R5 (spill-free gload_lds MFMA + XCD swizzle).

#define NEGV -1000000000.0f

typedef __attribute__((ext_vector_type(8))) short short8v;  // 8 bf16 (4 VGPR)
typedef __attribute__((ext_vector_type(4))) float f32x4;

#define KDIM 12544
#define PL   (1024 * 12544)   // plane elems (1024 padded rows)

__device__ __forceinline__ unsigned short to_bf16(float f) {
    unsigned u = __float_as_uint(f);
    unsigned r = u + 0x7FFFu + ((u >> 16) & 1u);   // RNE
    return (unsigned short)(r >> 16);
}
__device__ __forceinline__ float bf2f(unsigned short s) {
    return __uint_as_float((unsigned)s << 16);
}
__device__ __forceinline__ void gload16(const void* gsrc, void* ldst) {
    __builtin_amdgcn_global_load_lds(
        (const __attribute__((address_space(1))) unsigned int*)gsrc,
        (__attribute__((address_space(3))) unsigned int*)ldst,
        16, 0, 0);
}

// ---------------- RoI align + 3-way bf16 split ----------------
__global__ __launch_bounds__(256) void roi_align_split3(const float* __restrict__ feat,
    const float* __restrict__ prop, unsigned short* __restrict__ Ap)
{
    int n = blockIdx.y;
    int p = blockIdx.x;
    int my = p / 7, mx = p % 7;
    float x1 = prop[n * 4 + 0] * 0.0625f;
    float y1 = prop[n * 4 + 1] * 0.0625f;
    float x2 = prop[n * 4 + 2] * 0.0625f;
    float y2 = prop[n * 4 + 3] * 0.0625f;
    float rw = fmaxf(x2 - x1, 1.0f), rh = fmaxf(y2 - y1, 1.0f);
    float y = y1 + ((float)my + 0.5f) * (rh / 7.0f);
    float x = x1 + ((float)mx + 0.5f) * (rw / 7.0f);
    bool oob = (y < -1.0f) || (y > 50.0f) || (x < -1.0f) || (x > 50.0f);
    y = fminf(fmaxf(y, 0.0f), 49.0f);
    x = fminf(fmaxf(x, 0.0f), 49.0f);
    int y0 = (int)floorf(y), x0 = (int)floorf(x);
    int y1i = min(y0 + 1, 49), x1i = min(x0 + 1, 49);
    float ly = y - (float)y0, lx = x - (float)x0;
    float hy = 1.0f - ly, hx = 1.0f - lx;
    int c = threadIdx.x;
    float v = feat[(y0 * 50 + x0) * 256 + c] * (hy * hx)
            + feat[(y0 * 50 + x1i) * 256 + c] * (hy * lx)
            + feat[(y1i * 50 + x0) * 256 + c] * (ly * hx)
            + feat[(y1i * 50 + x1i) * 256 + c] * (ly * lx);
    if (oob) v = 0.0f;
    unsigned short s1 = to_bf16(v);  float r  = v - bf2f(s1);
    unsigned short s2 = to_bf16(r);  float r2 = r - bf2f(s2);
    unsigned short s3 = to_bf16(r2);
    size_t o = (size_t)n * KDIM + p * 256 + c;
    Ap[o] = s1; Ap[PL + o] = s2; Ap[2 * (size_t)PL + o] = s3;
}

// zero rows 1000..1023 of the 3 A-planes
__global__ __launch_bounds__(256) void zero_padA(unsigned short* __restrict__ Ap)
{
    int id = blockIdx.x * 256 + threadIdx.x;     // < 3*24*1568
    int p = id / 37632;
    int rem = id - p * 37632;
    int r = rem / 1568, c8 = rem - r * 1568;
    *(uint4*)&Ap[(size_t)p * PL + (size_t)(1000 + r) * KDIM + c8 * 8] =
        make_uint4(0, 0, 0, 0);
}

// ---------------- w1 -> 3 bf16 planes, permuted + transposed ----------------
__global__ __launch_bounds__(256) void conv_w1_k(const float* __restrict__ w1,
    unsigned short* __restrict__ Bt)
{
    __shared__ unsigned short T[3][64][72];
    int k0 = blockIdx.x * 64;
    int n0 = blockIdx.y * 64;
    int t = threadIdx.x;
#pragma unroll
    for (int j = 0; j < 16; ++j) {
        int idx = t + 256 * j;
        int n_l = idx & 63, k_l = idx >> 6;
        int kp = k0 + k_l;
        int orow = (kp & 255) * 49 + (kp >> 8);
        float v = w1[(size_t)orow * 1024 + n0 + n_l];
        unsigned short s1 = to_bf16(v);  float r  = v - bf2f(s1);
        unsigned short s2 = to_bf16(r);  float r2 = r - bf2f(s2);
        T[0][k_l][n_l] = s1;
        T[1][k_l][n_l] = s2;
        T[2][k_l][n_l] = to_bf16(r2);
    }
    __syncthreads();
#pragma unroll
    for (int p = 0; p < 3; ++p)
#pragma unroll
        for (int jj = 0; jj < 2; ++jj) {
            int w = t + 256 * jj;
            int n_l = w >> 3, kg = w & 7;
            short8v pk;
#pragma unroll
            for (int e = 0; e < 8; ++e) pk[e] = (short)T[p][kg * 8 + e][n_l];
            *(short8v*)&Bt[(size_t)p * PL + (size_t)(n0 + n_l) * KDIM + k0 + kg * 8] = pk;
        }
}

// ---------------- split-3 bf16 MFMA GEMM (GEMM1) ----------------
__global__ __launch_bounds__(256, 3) void gemm_mfma_split3(
    const unsigned short* __restrict__ Ap, const unsigned short* __restrict__ Bp,
    float* __restrict__ part, int Ks)
{
    __shared__ unsigned short ldsb[24576];   // 48 KB: A 3x128x32 | B 3x128x32

    int b = blockIdx.x;
    int xcd = b & 7;
    int rest = b >> 3;
    int m = rest & 7;
    int qhi = rest >> 3;
    int q = xcd + 8 * qhi;
    int z  = q >> 3;
    int qz = q & 7;
    int col0 = ((qz & 1) * 4 + (m & 3)) * 128;
    int row0 = ((qz >> 1) * 2 + (m >> 2)) * 128;
    int kOff = z * Ks;

    int t = threadIdx.x;
    int w = t >> 6;
    int lane = t & 63;
    int ln = lane & 15, g = lane >> 4;
    int wr = (w >> 1) * 64, wc = (w & 1) * 64;

    const unsigned short* smat = (w >= 2) ? Bp : Ap;
    int sbase = (w >= 2) ? col0 : row0;
    char* lbase = (char*)ldsb + ((w >= 2) ? 12288 * 2 : 0);
    int j0 = (w & 1) * 12;
    int srow_lane = lane >> 2;
    int scol_lane = (lane & 3) * 8;

    f32x4 acc[4][4] = {};
    const unsigned short* lds_us = ldsb;

    int nks = Ks >> 5;
    for (int ks = 0; ks < nks; ++ks) {
        int kpos = kOff + (ks << 5) + scol_lane;
#pragma unroll
        for (int ii = 0; ii < 12; ++ii) {
            int j = j0 + ii;
            int p = j >> 3, rb = j & 7;
            const unsigned short* src = smat + (size_t)p * PL
                + (size_t)(sbase + rb * 16 + srow_lane) * KDIM + kpos;
            gload16(src, lbase + p * 8192 + rb * 1024);
        }
        __syncthreads();
#pragma unroll
        for (int pb = 0; pb < 3; ++pb) {
            short8v bf[4];
#pragma unroll
            for (int fc = 0; fc < 4; ++fc)
                bf[fc] = *(const short8v*)&lds_us[12288 + pb * 4096 + (wc + fc * 16 + ln) * 32 + g * 8];
#pragma unroll
            for (int pa = 0; pa < 3; ++pa) {
                if (pa + pb >= 3) break;
                short8v af[4];
#pragma unroll
                for (int fr = 0; fr < 4; ++fr)
                    af[fr] = *(const short8v*)&lds_us[pa * 4096 + (wr + fr * 16 + ln) * 32 + g * 8];
#pragma unroll
                for (int fr = 0; fr < 4; ++fr)
#pragma unroll
                    for (int fc = 0; fc < 4; ++fc)
                        acc[fr][fc] = __builtin_amdgcn_mfma_f32_16x16x32_bf16(
                            af[fr], bf[fc], acc[fr][fc], 0, 0, 0);
            }
        }
        __syncthreads();
    }
    float* dst = part + (size_t)z * (1024 * 1024);
    int rbase = row0 + wr, cbase = col0 + wc;
#pragma unroll
    for (int fr = 0; fr < 4; ++fr)
#pragma unroll
        for (int fc = 0; fc < 4; ++fc)
#pragma unroll
            for (int reg = 0; reg < 4; ++reg)
                dst[(size_t)(rbase + fr * 16 + g * 4 + reg) * 1024 + cbase + fc * 16 + ln] =
                    acc[fr][fc][reg];
}

// ---------------- fp32 split-K GEMM (GEMM2) ----------------
__global__ __launch_bounds__(256) void gemm_splitk(const float* __restrict__ A,
    const float* __restrict__ B, float* __restrict__ part,
    int Mdim, int Ndim, int Kdim, int Ks, int permute)
{
    __shared__ float As[32][68];
    __shared__ float Bs[32][128];
    int tid = threadIdx.x;
    int col0 = blockIdx.x * 128;
    int row0 = blockIdx.y * 64;
    int kOff = blockIdx.z * Ks;
    int ty = tid >> 4, tx = tid & 15;
    int ar0 = tid >> 3;
    int af  = tid & 7;
    int aswz = (af & 3) << 3;
    int bkr0 = tid >> 5;
    int bf   = tid & 31;
    float4 pa0, pa1, pb0, pb1, pb2, pb3;

    auto loadA = [&](int k0) {
        int gr0 = row0 + ar0;
        int gr1 = gr0 + 32;
        pa0 = make_float4(0.f, 0.f, 0.f, 0.f);
        pa1 = make_float4(0.f, 0.f, 0.f, 0.f);
        if (gr0 < Mdim) pa0 = *(const float4*)&A[(size_t)gr0 * Kdim + kOff + k0 + af * 4];
        if (gr1 < Mdim) pa1 = *(const float4*)&A[(size_t)gr1 * Kdim + kOff + k0 + af * 4];
    };
    auto rowB = [&](int k0, int i) {
        int kg = kOff + k0 + bkr0 + 8 * i;
        int brv = permute ? ((kg & 255) * 49 + (kg >> 8)) : kg;
        return (const float4*)&B[(size_t)brv * Ndim + col0 + bf * 4];
    };
    auto loadB = [&](int k0) {
        pb0 = *rowB(k0, 0);
        pb1 = *rowB(k0, 1);
        pb2 = *rowB(k0, 2);
        pb3 = *rowB(k0, 3);
    };
    auto store = [&]() {
        int rc0 = ar0 ^ aswz;
        int rc1 = (ar0 + 32) ^ aswz;
        As[af * 4 + 0][rc0] = pa0.x;
        As[af * 4 + 1][rc0] = pa0.y;
        As[af * 4 + 2][rc0] = pa0.z;
        As[af * 4 + 3][rc0] = pa0.w;
        As[af * 4 + 0][rc1] = pa1.x;
        As[af * 4 + 1][rc1] = pa1.y;
        As[af * 4 + 2][rc1] = pa1.z;
        As[af * 4 + 3][rc1] = pa1.w;
        *(float4*)&Bs[bkr0 +  0][bf * 4] = pb0;
        *(float4*)&Bs[bkr0 +  8][bf * 4] = pb1;
        *(float4*)&Bs[bkr0 + 16][bf * 4] = pb2;
        *(float4*)&Bs[bkr0 + 24][bf * 4] = pb3;
    };

    float acc[4][8] = {};
    loadA(0); loadB(0);
    for (int k0 = 0; k0 < Ks; k0 += 32) {
        __syncthreads();
        store();
        __syncthreads();
        if (k0 + 32 < Ks) { loadA(k0 + 32); loadB(k0 + 32); }
#pragma unroll 8
        for (int kk = 0; kk < 32; ++kk) {
            int sa = ((kk >> 2) & 3) << 3;
            float4 a  = *(const float4*)&As[kk][(ty * 4) ^ sa];
            float4 b0 = *(const float4*)&Bs[kk][tx * 4];
            float4 b1 = *(const float4*)&Bs[kk][64 + tx * 4];
            float ar[4] = {a.x, a.y, a.z, a.w};
            float br[8] = {b0.x, b0.y, b0.z, b0.w, b1.x, b1.y, b1.z, b1.w};
#pragma unroll
            for (int i2 = 0; i2 < 4; ++i2)
#pragma unroll
                for (int j = 0; j < 8; ++j)
                    acc[i2][j] += ar[i2] * br[j];
        }
    }
    float* dst = part + (size_t)blockIdx.z * Mdim * Ndim;
    int gcA = col0 + tx * 4, gcB = col0 + 64 + tx * 4;
#pragma unroll
    for (int i2 = 0; i2 < 4; ++i2) {
        int gr = row0 + ty * 4 + i2;
        if (gr < Mdim) {
            *(float4*)&dst[(size_t)gr * Ndim + gcA] =
                make_float4(acc[i2][0], acc[i2][1], acc[i2][2], acc[i2][3]);
            *(float4*)&dst[(size_t)gr * Ndim + gcB] =
                make_float4(acc[i2][4], acc[i2][5], acc[i2][6], acc[i2][7]);
        }
    }
}

// ---------------- split-K reduce + bias + relu ----------------
__global__ __launch_bounds__(256) void reduce_bias_relu_k(const float* __restrict__ part,
    const float* __restrict__ bias, float* __restrict__ outp, int Ndim, int S, int MN)
{
    int m = blockIdx.x, t = threadIdx.x;
    size_t o = (size_t)m * Ndim + t * 4;
    float4 acc = *(const float4*)&part[o];
    for (int s = 1; s < S; ++s) {
        float4 p = *(const float4*)&part[(size_t)s * MN + o];
        acc.x += p.x; acc.y += p.y; acc.z += p.z; acc.w += p.w;
    }
    float4 bv = *(const float4*)&bias[t * 4];
    acc.x = fmaxf(acc.x + bv.x, 0.f);
    acc.y = fmaxf(acc.y + bv.y, 0.f);
    acc.z = fmaxf(acc.z + bv.z, 0.f);
    acc.w = fmaxf(acc.w + bv.w, 0.f);
    *(float4*)&outp[o] = acc;
}

// ---------------- cls/box heads ----------------
__global__ __launch_bounds__(128) void heads_k(const float* __restrict__ h,
    const float* __restrict__ w_cls, const float* __restrict__ b_cls,
    const float* __restrict__ w_box, const float* __restrict__ b_box,
    float* __restrict__ logits, float* __restrict__ deltas)
{
    __shared__ float sh[1024];
    int n = blockIdx.x;
    for (int i = threadIdx.x; i < 1024; i += 128) sh[i] = h[(size_t)n * 1024 + i];
    __syncthreads();
    int j = threadIdx.x;
    if (j < 21) {
        float acc = b_cls[j];
        for (int k = 0; k < 1024; ++k) acc += sh[k] * w_cls[k * 21 + j];
        logits[n * 21 + j] = acc;
    } else if (j < 105) {
        int jj = j - 21;
        float acc = b_box[jj];
        for (int k = 0; k < 1024; ++k) acc += sh[k] * w_box[k * 84 + jj];
        deltas[n * 84 + jj] = acc;
    }
}

// ---------------- softmax + decode + clip + mask ----------------
__global__ __launch_bounds__(64) void postproc_k(const float* __restrict__ logits,
    const float* __restrict__ deltas, const float* __restrict__ prop,
    const int* __restrict__ img_h_p, const int* __restrict__ img_w_p,
    float* __restrict__ scores_m, float* __restrict__ boxes_dec)
{
    int n = blockIdx.x;
    int cls = threadIdx.x;
    if (cls < 1 || cls > 20) return;
    float mx = -3.0e38f;
    for (int i = 0; i < 21; ++i) mx = fmaxf(mx, logits[n * 21 + i]);
    float sum = 0.f;
    for (int i = 0; i < 21; ++i) sum += expf(logits[n * 21 + i] - mx);
    float score = expf(logits[n * 21 + cls] - mx) / sum;

    float p0 = prop[n * 4 + 0], p1 = prop[n * 4 + 1];
    float p2 = prop[n * 4 + 2], p3 = prop[n * 4 + 3];
    float w = p2 - p0, h = p3 - p1;
    float cx = p0 + 0.5f * w, cy = p1 + 0.5f * h;
    float d0 = deltas[n * 84 + cls * 4 + 0];
    float d1 = deltas[n * 84 + cls * 4 + 1];
    float d2 = deltas[n * 84 + cls * 4 + 2];
    float d3 = deltas[n * 84 + cls * 4 + 3];
    const float CLIP = 4.135166556742356f;  // log(1000/16)
    float dx = d0 / 10.0f, dy = d1 / 10.0f;
    float dw = fminf(d2 / 5.0f, CLIP), dh = fminf(d3 / 5.0f, CLIP);
    float pcx = dx * w + cx, pcy = dy * h + cy;
    float pw = expf(dw) * w, ph = expf(dh) * h;
    float bx1 = pcx - 0.5f * pw, by1 = pcy - 0.5f * ph;
    float bx2 = pcx + 0.5f * pw, by2 = pcy + 0.5f * ph;
    float iw = (float)img_w_p[0], ih = (float)img_h_p[0];
    bx1 = fminf(fmaxf(bx1, 0.f), iw);
    by1 = fminf(fmaxf(by1, 0.f), ih);
    bx2 = fminf(fmaxf(bx2, 0.f), iw);
    by2 = fminf(fmaxf(by2, 0.f), ih);
    float bw = bx2 - bx1, bh = by2 - by1;
    bool keep = (bw >= 1.0f) && (bh >= 1.0f) && (score >= 0.05f);
    int o = (cls - 1) * 1000 + n;
    scores_m[o] = keep ? score : NEGV;
    ((float4*)boxes_dec)[o] = make_float4(bx1, by1, bx2, by2);
}

// ---------------- NMS stage 1: bitonic sort by (score desc, idx asc) -------
// 20 blocks x 256 thr. keys u64 = (transform(score)<<32)|(1023-idx); sort
// ascending on ~key. Emits sorted boxes/scores [1024] + valid count V.
__global__ __launch_bounds__(256) void nms_sort_k(const float* __restrict__ scores_m,
    const float* __restrict__ boxes_dec, float* __restrict__ sboxes,
    float* __restrict__ sscore, int* __restrict__ Vcnt)
{
    __shared__ unsigned long long sk[1024];
    __shared__ int cnt;
    int cls = blockIdx.x, t = threadIdx.x;
    if (t == 0) cnt = 0;
    __syncthreads();
    for (int r = t; r < 1024; r += 256) {
        unsigned long long inv = ~0ull;
        if (r < 1000) {
            float v = scores_m[cls * 1000 + r];
            unsigned ub = __float_as_uint(v);
            ub = (ub & 0x80000000u) ? ~ub : (ub | 0x80000000u);
            inv = ~(((unsigned long long)ub << 32) | (unsigned)(1023 - r));
            if (v > 0.5f * NEGV) atomicAdd(&cnt, 1);
        }
        sk[r] = inv;
    }
    __syncthreads();
    for (int k = 2; k <= 1024; k <<= 1) {
        for (int j = k >> 1; j > 0; j >>= 1) {
            for (int pi = t; pi < 512; pi += 256) {
                int i = ((pi & ~(j - 1)) << 1) | (pi & (j - 1));
                int p = i | j;
                bool up = ((i & k) == 0);
                unsigned long long a = sk[i], b2 = sk[p];
                if ((a > b2) == up) { sk[i] = b2; sk[p] = a; }
            }
            __syncthreads();
        }
    }
    for (int r = t; r < 1024; r += 256) {
        unsigned long long key = ~sk[r];
        unsigned ub = (unsigned)(key >> 32);
        int idx = 1023 - (int)(key & 1023u);
        float4 bx = make_float4(0.f, 0.f, 0.f, 0.f);
        float scv = NEGV;
        if (key != 0ull && idx < 1000) {
            bx = ((const float4*)boxes_dec)[cls * 1000 + idx];
            unsigned u = (ub & 0x80000000u) ? (ub & 0x7FFFFFFFu) : ~ub;
            scv = __uint_as_float(u);
        }
        ((float4*)sboxes)[(size_t)cls * 1024 + r] = bx;
        sscore[(size_t)cls * 1024 + r] = scv;
    }
    if (t == 0) Vcnt[cls] = cnt;
}

// ---------------- NMS stage 2: IoU bitmask rows ----------------
// grid = 20*16 blocks (class, 64-row chunk) x 256 thr. mask[c][i][w] (u64,
// w<16) = sorted-j in word w with j>i && IoU>0.5. All 16 words written.
__global__ __launch_bounds__(256) void nms_mask_k(const float* __restrict__ sboxes,
    unsigned long long* __restrict__ mask)
{
    __shared__ float4 colb[1024];
    __shared__ float area[1024];
    int cls = blockIdx.x >> 4;
    int chunk = blockIdx.x & 15;
    int t = threadIdx.x;
    const float4* sb = (const float4*)sboxes + (size_t)cls * 1024;
    for (int j = t; j < 1024; j += 256) {
        float4 b = sb[j];
        colb[j] = b;
        area[j] = (b.z - b.x) * (b.w - b.y);
    }
    __syncthreads();
    int row_l = t >> 2;
    int qt = t & 3;
    int i = chunk * 64 + row_l;
    float4 rb = colb[i];
    float a1 = area[i];
    unsigned long long* dst = mask + ((size_t)cls * 1024 + i) * 16 + qt * 4;
#pragma unroll
    for (int w = 0; w < 4; ++w) {
        unsigned long long wv = 0;
        int jb = qt * 256 + w * 64;
#pragma unroll 8
        for (int bi = 0; bi < 64; ++bi) {
            int j = jb + bi;
            float4 cb = colb[j];
            float ltx = fmaxf(rb.x, cb.x), lty = fmaxf(rb.y, cb.y);
            float rbx = fminf(rb.z, cb.z), rby = fminf(rb.w, cb.w);
            float wiw = fmaxf(rbx - ltx, 0.f), wih = fmaxf(rby - lty, 0.f);
            float inter = wiw * wih;
            float iou = inter / (a1 + area[j] - inter + 1e-9f);
            if (j > i && iou > 0.5f) wv |= (1ull << bi);
        }
        dst[w] = wv;
    }
}

// ---------------- NMS stage 3: greedy sweep ----------------
// 20 blocks x 64 thr (1 wave). suppr bitset lane-sliced (lane w<16 owns word
// w); per row: ballot bit-check (~20cyc); kept -> lane-local OR of mask row.
__global__ __launch_bounds__(64) void nms_sweep_k(const float* __restrict__ sboxes,
    const float* __restrict__ sscore, const int* __restrict__ Vcnt,
    const unsigned long long* __restrict__ mask, float* __restrict__ out)
{
    int cls = blockIdx.x;
    int lane = threadIdx.x;
    __shared__ int keptlist[100];
    int V = Vcnt[cls];
    const unsigned long long* mbase = mask + (size_t)cls * 1024 * 16;
    unsigned long long suppr = 0;
    int kept = 0;
    int nb = (V + 15) >> 4;
    for (int b = 0; b < nb && kept < 100; ++b) {
        unsigned long long L[16];
#pragma unroll
        for (int k = 0; k < 16; ++k)
            L[k] = mbase[(size_t)(b * 16 + k) * 16 + (lane & 15)];
#pragma unroll
        for (int k = 0; k < 16; ++k) {
            int i = b * 16 + k;
            if (i < V && kept < 100) {
                bool sup = (lane == (i >> 6)) && ((suppr >> (i & 63)) & 1ull);
                if (__ballot(sup) == 0ull) {
                    if (lane == 0) keptlist[kept] = i;
                    if (lane < 16) suppr |= L[k];
                    ++kept;
                }
            }
        }
    }
    __syncthreads();
    float* kb   = out;            // [2000][4]
    float* ksc  = out + 8000;     // [2000]
    float* klab = out + 10000;    // [2000]
    for (int s = lane; s < 100; s += 64) {
        klab[cls * 100 + s] = (float)(cls + 1);
        if (s < kept) {
            int r = keptlist[s];
            ((float4*)kb)[cls * 100 + s] =
                ((const float4*)sboxes)[(size_t)cls * 1024 + r];
            ksc[cls * 100 + s] = sscore[(size_t)cls * 1024 + r];
        } else {
            ((float4*)kb)[cls * 100 + s] = make_float4(0.f, 0.f, 0.f, 0.f);
            ksc[cls * 100 + s] = 0.f;
        }
    }
}

extern "C" void kernel_launch(void* const* d_in, const int* in_sizes, int n_in,
                              void* d_out, int out_size, void* d_ws, size_t ws_size,
                              hipStream_t stream)
{
    const float* feat  = (const float*)d_in[0];
    const float* prop  = (const float*)d_in[1];
    const float* w1    = (const float*)d_in[2];
    const float* b1    = (const float*)d_in[3];
    const float* w2    = (const float*)d_in[4];
    const float* b2    = (const float*)d_in[5];
    const float* w_cls = (const float*)d_in[6];
    const float* b_cls = (const float*)d_in[7];
    const float* w_box = (const float*)d_in[8];
    const float* b_box = (const float*)d_in[9];
    const int* img_h   = (const int*)d_in[10];
    const int* img_w   = (const int*)d_in[11];

    char* wsb = (char*)d_ws;
    unsigned short* Apl = (unsigned short*)wsb;                    // 77,070,336 B
    unsigned short* Bpl = (unsigned short*)(wsb + 77070336);       // 77,070,336 B
    float* part   = (float*)(wsb + 154140672);                     // 33,554,432 B
    float* h1     = (float*)(wsb + 187695104);
    float* h2     = (float*)(wsb + 191791104);
    float* logits = (float*)(wsb + 195887104);
    float* deltas = (float*)(wsb + 195971104);
    float* scores_m  = (float*)(wsb + 196307104);
    float* boxes_dec = (float*)(wsb + 196387104);
    // NMS scratch aliases the (dead-by-then) part region:
    unsigned long long* nmask = (unsigned long long*)(wsb + 154140672); // 2,621,440 B
    float* sboxes = (float*)(wsb + 156762112);                          //   327,680 B
    float* sscore = (float*)(wsb + 157089792);                          //    81,920 B
    int*   Vcnt   = (int*)(wsb + 157171712);                            //        80 B
    float* outp = (float*)d_out;

    hipLaunchKernelGGL(roi_align_split3, dim3(49, 1000), dim3(256), 0, stream,
                       feat, prop, Apl);
    hipLaunchKernelGGL(zero_padA, dim3(441), dim3(256), 0, stream, Apl);
    hipLaunchKernelGGL(conv_w1_k, dim3(196, 16), dim3(256), 0, stream, w1, Bpl);
    hipLaunchKernelGGL(gemm_mfma_split3, dim3(512), dim3(256), 0, stream,
                       Apl, Bpl, part, 1568);
    hipLaunchKernelGGL(reduce_bias_relu_k, dim3(1000), dim3(256), 0, stream,
                       part, b1, h1, 1024, 8, 1024 * 1024);
    hipLaunchKernelGGL(gemm_splitk, dim3(8, 16, 4), dim3(256), 0, stream,
                       h1, w2, part, 1000, 1024, 1024, 256, 0);
    hipLaunchKernelGGL(reduce_bias_relu_k, dim3(1000), dim3(256), 0, stream,
                       part, b2, h2, 1024, 4, 1024000);
    hipLaunchKernelGGL(heads_k, dim3(1000), dim3(128), 0, stream,
                       h2, w_cls, b_cls, w_box, b_box, logits, deltas);
    hipLaunchKernelGGL(postproc_k, dim3(1000), dim3(64), 0, stream,
                       logits, deltas, prop, img_h, img_w, scores_m, boxes_dec);
    hipLaunchKernelGGL(nms_sort_k, dim3(20), dim3(256), 0, stream,
                       scores_m, boxes_dec, sboxes, sscore, Vcnt);
    hipLaunchKernelGGL(nms_mask_k, dim3(320), dim3(256), 0, stream, sboxes, nmask);
    hipLaunchKernelGGL(nms_sweep_k, dim3(20), dim3(64), 0, stream,
                       sboxes, sscore, Vcnt, nmask, outp);
}

// Round 7
// 442.832 us; speedup vs baseline: 2.1550x; 1.1620x over previous
//
#include <hip/hip_runtime.h>

// RoIHeads pipeline: roi_align -> FC1(relu) -> FC2(relu) -> cls/box heads ->
// softmax/decode/clip/mask -> per-class NMS.
//
// R7 (from R6 rocprof: gemm1 138us, MfmaUtil 51%, 9.6e6 bank conflicts;
// tail ~377us = heads/gemm2/converters):
//  - GEMM1: 2-phase double-buffer (96KB dynamic LDS, stage t+1 before
//    compute t, 1 barrier/iter) + T2 XOR swizzle (source-side pre-swizzle,
//    linear gload_lds dest, XOR'd read slot): 8-way -> 2-way conflicts.
//  - GEMM2 and cls/box heads moved to the same split-3 bf16 MFMA kernel
//    (generalized dims); reduce kernels emit split-3 planes directly.
//    heads = 1024x128x1024 GEMM over packed [w_cls|w_box]; postproc reads
//    the fused [n][128] head output. fp32 gemm_splitk + heads_k deleted.

#define NEGV -1000000000.0f

typedef __attribute__((ext_vector_type(8))) short short8v;  // 8 bf16 (4 VGPR)
typedef __attribute__((ext_vector_type(4))) float f32x4;

#define KDIM 12544
#define PL   (1024 * 12544)   // GEMM1 plane elems (1024 padded rows)

__device__ __forceinline__ unsigned short to_bf16(float f) {
    unsigned u = __float_as_uint(f);
    unsigned r = u + 0x7FFFu + ((u >> 16) & 1u);   // RNE
    return (unsigned short)(r >> 16);
}
__device__ __forceinline__ float bf2f(unsigned short s) {
    return __uint_as_float((unsigned)s << 16);
}
__device__ __forceinline__ void gload16(const void* gsrc, void* ldst) {
    __builtin_amdgcn_global_load_lds(
        (const __attribute__((address_space(1))) unsigned int*)gsrc,
        (__attribute__((address_space(3))) unsigned int*)ldst,
        16, 0, 0);
}

// ---------------- RoI align + 3-way bf16 split ----------------
// (pad rows 1000..1023 of A planes stay poisoned: they only affect unused
//  C rows -> zero_padA dropped)
__global__ __launch_bounds__(256) void roi_align_split3(const float* __restrict__ feat,
    const float* __restrict__ prop, unsigned short* __restrict__ Ap)
{
    int n = blockIdx.y;
    int p = blockIdx.x;
    int my = p / 7, mx = p % 7;
    float x1 = prop[n * 4 + 0] * 0.0625f;
    float y1 = prop[n * 4 + 1] * 0.0625f;
    float x2 = prop[n * 4 + 2] * 0.0625f;
    float y2 = prop[n * 4 + 3] * 0.0625f;
    float rw = fmaxf(x2 - x1, 1.0f), rh = fmaxf(y2 - y1, 1.0f);
    float y = y1 + ((float)my + 0.5f) * (rh / 7.0f);
    float x = x1 + ((float)mx + 0.5f) * (rw / 7.0f);
    bool oob = (y < -1.0f) || (y > 50.0f) || (x < -1.0f) || (x > 50.0f);
    y = fminf(fmaxf(y, 0.0f), 49.0f);
    x = fminf(fmaxf(x, 0.0f), 49.0f);
    int y0 = (int)floorf(y), x0 = (int)floorf(x);
    int y1i = min(y0 + 1, 49), x1i = min(x0 + 1, 49);
    float ly = y - (float)y0, lx = x - (float)x0;
    float hy = 1.0f - ly, hx = 1.0f - lx;
    int c = threadIdx.x;
    float v = feat[(y0 * 50 + x0) * 256 + c] * (hy * hx)
            + feat[(y0 * 50 + x1i) * 256 + c] * (hy * lx)
            + feat[(y1i * 50 + x0) * 256 + c] * (ly * hx)
            + feat[(y1i * 50 + x1i) * 256 + c] * (ly * lx);
    if (oob) v = 0.0f;
    unsigned short s1 = to_bf16(v);  float r  = v - bf2f(s1);
    unsigned short s2 = to_bf16(r);  float r2 = r - bf2f(s2);
    unsigned short s3 = to_bf16(r2);
    size_t o = (size_t)n * KDIM + p * 256 + c;
    Ap[o] = s1; Ap[PL + o] = s2; Ap[2 * (size_t)PL + o] = s3;
}

// ---------------- fp32 [K][1024] -> 3 bf16 planes, transposed [1024][Ktot] --
// perm!=0: logical k' -> physical src row (k'&255)*49 + (k'>>8) (GEMM1 w1).
__global__ __launch_bounds__(256) void convT_k(const float* __restrict__ src,
    unsigned short* __restrict__ dst, int perm, int Ktot)
{
    __shared__ unsigned short T[3][64][72];
    int k0 = blockIdx.x * 64;
    int n0 = blockIdx.y * 64;
    int t = threadIdx.x;
    size_t plst = (size_t)1024 * Ktot;
#pragma unroll
    for (int j = 0; j < 16; ++j) {
        int idx = t + 256 * j;
        int n_l = idx & 63, k_l = idx >> 6;
        int kp = k0 + k_l;
        int orow = perm ? ((kp & 255) * 49 + (kp >> 8)) : kp;
        float v = src[(size_t)orow * 1024 + n0 + n_l];
        unsigned short s1 = to_bf16(v);  float r  = v - bf2f(s1);
        unsigned short s2 = to_bf16(r);  float r2 = r - bf2f(s2);
        T[0][k_l][n_l] = s1;
        T[1][k_l][n_l] = s2;
        T[2][k_l][n_l] = to_bf16(r2);
    }
    __syncthreads();
#pragma unroll
    for (int p = 0; p < 3; ++p)
#pragma unroll
        for (int jj = 0; jj < 2; ++jj) {
            int w = t + 256 * jj;
            int n_l = w >> 3, kg = w & 7;
            short8v pk;
#pragma unroll
            for (int e = 0; e < 8; ++e) pk[e] = (short)T[p][kg * 8 + e][n_l];
            *(short8v*)&dst[p * plst + (size_t)(n0 + n_l) * Ktot + k0 + kg * 8] = pk;
        }
}

// ---------------- packed heads weights -> 3 planes [128][1024] ----------
__global__ __launch_bounds__(256) void conv_heads_k(const float* __restrict__ w_cls,
    const float* __restrict__ w_box, unsigned short* __restrict__ Bth)
{
    int id = blockIdx.x * 256 + threadIdx.x;   // < 128*1024
    int j = id >> 10, k = id & 1023;
    float v = 0.f;
    if (j < 21) v = w_cls[k * 21 + j];
    else if (j < 105) v = w_box[k * 84 + (j - 21)];
    unsigned short s1 = to_bf16(v);  float r  = v - bf2f(s1);
    unsigned short s2 = to_bf16(r);  float r2 = r - bf2f(s2);
    Bth[id] = s1; Bth[131072 + id] = s2; Bth[262144 + id] = to_bf16(r2);
}

// ---------------- split-3 bf16 MFMA GEMM body (2-phase dbuf + T2 swizzle) --
// A planes [1024][K], B planes [N][K] (transposed), part[z][1024][N].
// BM=BN=128, BK=32, 4 waves. LDS dyn 96KB: buf x (A 3x8KB | B 3x8KB).
// Swizzle: slot(row,g) holds chunk g^((row>>1)&3); gload_lds dest linear,
// source pre-swizzled (rule #21) -> 2-way (free) frag reads.
__device__ __forceinline__ void gemm_body(const unsigned short* __restrict__ Ap,
    const unsigned short* __restrict__ Bp, float* __restrict__ part,
    int K, int Ks, int nks, size_t plA, size_t plB, int N,
    int col0, int row0, int z, unsigned short* lds)
{
    int t = threadIdx.x;
    int w = t >> 6, lane = t & 63;
    int ln = lane & 15, g = lane >> 4;
    int wr = (w >> 1) * 64, wc = (w & 1) * 64;

    const unsigned short* smat = (w >= 2) ? Bp : Ap;
    size_t spl = (w >= 2) ? plB : plA;
    int sbase = (w >= 2) ? col0 : row0;
    int hoff = (w >= 2) ? 24576 : 0;
    int j0 = (w & 1) * 12;
    int srow = lane >> 2;
    int scol = ((lane & 3) ^ ((lane >> 3) & 3)) * 8;   // pre-swizzled source chunk
    int kOff = z * Ks;

    auto stage = [&](int buf, int ks) {
        char* lb = (char*)lds + buf * 49152 + hoff;
        int kpos = kOff + (ks << 5) + scol;
#pragma unroll
        for (int ii = 0; ii < 12; ++ii) {
            int j = j0 + ii;
            int p = j >> 3, rb = j & 7;
            const unsigned short* src = smat + (size_t)p * spl
                + (size_t)(sbase + rb * 16 + srow) * K + kpos;
            gload16(src, lb + p * 8192 + rb * 1024);
        }
    };

    f32x4 acc[4][4] = {};
    stage(0, 0);
    __syncthreads();
    int buf = 0;
    for (int ks = 0; ks < nks; ++ks) {
        if (ks + 1 < nks) stage(buf ^ 1, ks + 1);   // async, lands by barrier
        const unsigned short* la  = (const unsigned short*)((char*)lds + buf * 49152);
        const unsigned short* lbB = (const unsigned short*)((char*)lds + buf * 49152 + 24576);
#pragma unroll
        for (int pb = 0; pb < 3; ++pb) {
            short8v bf[4];
#pragma unroll
            for (int fc = 0; fc < 4; ++fc) {
                int r = wc + fc * 16 + ln;
                bf[fc] = *(const short8v*)&lbB[pb * 4096 + r * 32 + ((g ^ ((r >> 1) & 3)) << 3)];
            }
#pragma unroll
            for (int pa = 0; pa < 3 - pb; ++pa) {
                short8v af[4];
#pragma unroll
                for (int fr = 0; fr < 4; ++fr) {
                    int r = wr + fr * 16 + ln;
                    af[fr] = *(const short8v*)&la[pa * 4096 + r * 32 + ((g ^ ((r >> 1) & 3)) << 3)];
                }
#pragma unroll
                for (int fr = 0; fr < 4; ++fr)
#pragma unroll
                    for (int fc = 0; fc < 4; ++fc)
                        acc[fr][fc] = __builtin_amdgcn_mfma_f32_16x16x32_bf16(
                            af[fr], bf[fc], acc[fr][fc], 0, 0, 0);
            }
        }
        __syncthreads();     // drains vmcnt (next tile ready) + read-done
        buf ^= 1;
    }
    float* dst = part + (size_t)z * 1024 * N;
    int rbase = row0 + wr, cbase = col0 + wc;
#pragma unroll
    for (int fr = 0; fr < 4; ++fr)
#pragma unroll
        for (int fc = 0; fc < 4; ++fc)
#pragma unroll
            for (int reg = 0; reg < 4; ++reg)
                dst[(size_t)(rbase + fr * 16 + g * 4 + reg) * N + cbase + fc * 16 + ln] =
                    acc[fr][fc][reg];
}

// GEMM1 wrapper: 512 blocks 1D with XCD cluster swizzle (verified R5/R6).
__global__ __launch_bounds__(256, 1) void gemm1_k(const unsigned short* __restrict__ Ap,
    const unsigned short* __restrict__ Bp, float* __restrict__ part)
{
    extern __shared__ unsigned short ldsdyn[];
    int b = blockIdx.x;
    int xcd = b & 7;
    int rest = b >> 3;
    int m = rest & 7;
    int qhi = rest >> 3;
    int q = xcd + 8 * qhi;
    int z  = q >> 3;
    int qz = q & 7;
    int col0 = ((qz & 1) * 4 + (m & 3)) * 128;
    int row0 = ((qz >> 1) * 2 + (m >> 2)) * 128;
    gemm_body(Ap, Bp, part, KDIM, 1568, 49, (size_t)PL, (size_t)PL, 1024,
              col0, row0, z, ldsdyn);
}

// generic wrapper: grid (N/128, 8, S)
__global__ __launch_bounds__(256, 1) void gemm_g_k(const unsigned short* __restrict__ Ap,
    const unsigned short* __restrict__ Bp, float* __restrict__ part,
    int K, int Ks, int nks, int plA, int plB, int N)
{
    extern __shared__ unsigned short ldsdyn[];
    gemm_body(Ap, Bp, part, K, Ks, nks, (size_t)plA, (size_t)plB, N,
              blockIdx.x * 128, blockIdx.y * 128, blockIdx.z, ldsdyn);
}

// ---------------- split-K reduce + bias + relu -> split-3 planes ----------
// grid 1000 x 256 thr; N=1024; plane stride 1048576 elems (bf16).
__global__ __launch_bounds__(256) void reduce_split3_k(const float* __restrict__ part,
    const float* __restrict__ bias, unsigned short* __restrict__ dstP, int S)
{
    int m = blockIdx.x, t = threadIdx.x;
    size_t o = (size_t)m * 1024 + t * 4;
    float4 acc = *(const float4*)&part[o];
    for (int s = 1; s < S; ++s) {
        float4 p = *(const float4*)&part[(size_t)s * 1048576 + o];
        acc.x += p.x; acc.y += p.y; acc.z += p.z; acc.w += p.w;
    }
    float4 bv = *(const float4*)&bias[t * 4];
    float vals[4] = { fmaxf(acc.x + bv.x, 0.f), fmaxf(acc.y + bv.y, 0.f),
                      fmaxf(acc.z + bv.z, 0.f), fmaxf(acc.w + bv.w, 0.f) };
    unsigned short o1[4], o2[4], o3[4];
#pragma unroll
    for (int e = 0; e < 4; ++e) {
        unsigned short s1 = to_bf16(vals[e]);  float r  = vals[e] - bf2f(s1);
        unsigned short s2 = to_bf16(r);        float r2 = r - bf2f(s2);
        o1[e] = s1; o2[e] = s2; o3[e] = to_bf16(r2);
    }
    *(uint2*)&dstP[o]           = *(uint2*)o1;
    *(uint2*)&dstP[1048576 + o] = *(uint2*)o2;
    *(uint2*)&dstP[2097152 + o] = *(uint2*)o3;
}

// ---------------- heads reduce: sum 8 partials + packed bias -> Hout ------
__global__ __launch_bounds__(128) void reduce_heads_k(const float* __restrict__ part,
    const float* __restrict__ b_cls, const float* __restrict__ b_box,
    float* __restrict__ Hout)
{
    int m = blockIdx.x, t = threadIdx.x;
    size_t o = (size_t)m * 128 + t;
    float a = part[o];
    for (int s = 1; s < 8; ++s) a += part[(size_t)s * 131072 + o];
    float b = (t < 21) ? b_cls[t] : (t < 105 ? b_box[t - 21] : 0.f);
    Hout[o] = a + b;
}

// ---------------- softmax + decode + clip + mask (reads fused Hout) ------
__global__ __launch_bounds__(64) void postproc_k(const float* __restrict__ H,
    const float* __restrict__ prop, const int* __restrict__ img_h_p,
    const int* __restrict__ img_w_p, float* __restrict__ scores_m,
    float* __restrict__ boxes_dec)
{
    int n = blockIdx.x;
    int cls = threadIdx.x;
    if (cls < 1 || cls > 20) return;
    const float* hn = H + (size_t)n * 128;
    float mx = -3.0e38f;
    for (int i = 0; i < 21; ++i) mx = fmaxf(mx, hn[i]);
    float sum = 0.f;
    for (int i = 0; i < 21; ++i) sum += expf(hn[i] - mx);
    float score = expf(hn[cls] - mx) / sum;

    float p0 = prop[n * 4 + 0], p1 = prop[n * 4 + 1];
    float p2 = prop[n * 4 + 2], p3 = prop[n * 4 + 3];
    float w = p2 - p0, h = p3 - p1;
    float cx = p0 + 0.5f * w, cy = p1 + 0.5f * h;
    float d0 = hn[21 + cls * 4 + 0];
    float d1 = hn[21 + cls * 4 + 1];
    float d2 = hn[21 + cls * 4 + 2];
    float d3 = hn[21 + cls * 4 + 3];
    const float CLIP = 4.135166556742356f;  // log(1000/16)
    float dx = d0 / 10.0f, dy = d1 / 10.0f;
    float dw = fminf(d2 / 5.0f, CLIP), dh = fminf(d3 / 5.0f, CLIP);
    float pcx = dx * w + cx, pcy = dy * h + cy;
    float pw = expf(dw) * w, ph = expf(dh) * h;
    float bx1 = pcx - 0.5f * pw, by1 = pcy - 0.5f * ph;
    float bx2 = pcx + 0.5f * pw, by2 = pcy + 0.5f * ph;
    float iw = (float)img_w_p[0], ih = (float)img_h_p[0];
    bx1 = fminf(fmaxf(bx1, 0.f), iw);
    by1 = fminf(fmaxf(by1, 0.f), ih);
    bx2 = fminf(fmaxf(bx2, 0.f), iw);
    by2 = fminf(fmaxf(by2, 0.f), ih);
    float bw = bx2 - bx1, bh = by2 - by1;
    bool keep = (bw >= 1.0f) && (bh >= 1.0f) && (score >= 0.05f);
    int o = (cls - 1) * 1000 + n;
    scores_m[o] = keep ? score : NEGV;
    ((float4*)boxes_dec)[o] = make_float4(bx1, by1, bx2, by2);
}

// ---------------- NMS stage 1: bitonic sort by (score desc, idx asc) -------
__global__ __launch_bounds__(256) void nms_sort_k(const float* __restrict__ scores_m,
    const float* __restrict__ boxes_dec, float* __restrict__ sboxes,
    float* __restrict__ sscore, int* __restrict__ Vcnt)
{
    __shared__ unsigned long long sk[1024];
    __shared__ int cnt;
    int cls = blockIdx.x, t = threadIdx.x;
    if (t == 0) cnt = 0;
    __syncthreads();
    for (int r = t; r < 1024; r += 256) {
        unsigned long long inv = ~0ull;
        if (r < 1000) {
            float v = scores_m[cls * 1000 + r];
            unsigned ub = __float_as_uint(v);
            ub = (ub & 0x80000000u) ? ~ub : (ub | 0x80000000u);
            inv = ~(((unsigned long long)ub << 32) | (unsigned)(1023 - r));
            if (v > 0.5f * NEGV) atomicAdd(&cnt, 1);
        }
        sk[r] = inv;
    }
    __syncthreads();
    for (int k = 2; k <= 1024; k <<= 1) {
        for (int j = k >> 1; j > 0; j >>= 1) {
            for (int pi = t; pi < 512; pi += 256) {
                int i = ((pi & ~(j - 1)) << 1) | (pi & (j - 1));
                int p = i | j;
                bool up = ((i & k) == 0);
                unsigned long long a = sk[i], b2 = sk[p];
                if ((a > b2) == up) { sk[i] = b2; sk[p] = a; }
            }
            __syncthreads();
        }
    }
    for (int r = t; r < 1024; r += 256) {
        unsigned long long key = ~sk[r];
        unsigned ub = (unsigned)(key >> 32);
        int idx = 1023 - (int)(key & 1023u);
        float4 bx = make_float4(0.f, 0.f, 0.f, 0.f);
        float scv = NEGV;
        if (key != 0ull && idx < 1000) {
            bx = ((const float4*)boxes_dec)[cls * 1000 + idx];
            unsigned u = (ub & 0x80000000u) ? (ub & 0x7FFFFFFFu) : ~ub;
            scv = __uint_as_float(u);
        }
        ((float4*)sboxes)[(size_t)cls * 1024 + r] = bx;
        sscore[(size_t)cls * 1024 + r] = scv;
    }
    if (t == 0) Vcnt[cls] = cnt;
}

// ---------------- NMS stage 2: IoU bitmask rows ----------------
__global__ __launch_bounds__(256) void nms_mask_k(const float* __restrict__ sboxes,
    unsigned long long* __restrict__ mask)
{
    __shared__ float4 colb[1024];
    __shared__ float area[1024];
    int cls = blockIdx.x >> 4;
    int chunk = blockIdx.x & 15;
    int t = threadIdx.x;
    const float4* sb = (const float4*)sboxes + (size_t)cls * 1024;
    for (int j = t; j < 1024; j += 256) {
        float4 b = sb[j];
        colb[j] = b;
        area[j] = (b.z - b.x) * (b.w - b.y);
    }
    __syncthreads();
    int row_l = t >> 2;
    int qt = t & 3;
    int i = chunk * 64 + row_l;
    float4 rb = colb[i];
    float a1 = area[i];
    unsigned long long* dst = mask + ((size_t)cls * 1024 + i) * 16 + qt * 4;
#pragma unroll
    for (int w = 0; w < 4; ++w) {
        unsigned long long wv = 0;
        int jb = qt * 256 + w * 64;
#pragma unroll 8
        for (int bi = 0; bi < 64; ++bi) {
            int j = jb + bi;
            float4 cb = colb[j];
            float ltx = fmaxf(rb.x, cb.x), lty = fmaxf(rb.y, cb.y);
            float rbx = fminf(rb.z, cb.z), rby = fminf(rb.w, cb.w);
            float wiw = fmaxf(rbx - ltx, 0.f), wih = fmaxf(rby - lty, 0.f);
            float inter = wiw * wih;
            float iou = inter / (a1 + area[j] - inter + 1e-9f);
            if (j > i && iou > 0.5f) wv |= (1ull << bi);
        }
        dst[w] = wv;
    }
}

// ---------------- NMS stage 3: greedy sweep ----------------
__global__ __launch_bounds__(64) void nms_sweep_k(const float* __restrict__ sboxes,
    const float* __restrict__ sscore, const int* __restrict__ Vcnt,
    const unsigned long long* __restrict__ mask, float* __restrict__ out)
{
    int cls = blockIdx.x;
    int lane = threadIdx.x;
    __shared__ int keptlist[100];
    int V = Vcnt[cls];
    const unsigned long long* mbase = mask + (size_t)cls * 1024 * 16;
    unsigned long long suppr = 0;
    int kept = 0;
    int nb = (V + 15) >> 4;
    for (int b = 0; b < nb && kept < 100; ++b) {
        unsigned long long L[16];
#pragma unroll
        for (int k = 0; k < 16; ++k)
            L[k] = mbase[(size_t)(b * 16 + k) * 16 + (lane & 15)];
#pragma unroll
        for (int k = 0; k < 16; ++k) {
            int i = b * 16 + k;
            if (i < V && kept < 100) {
                bool sup = (lane == (i >> 6)) && ((suppr >> (i & 63)) & 1ull);
                if (__ballot(sup) == 0ull) {
                    if (lane == 0) keptlist[kept] = i;
                    if (lane < 16) suppr |= L[k];
                    ++kept;
                }
            }
        }
    }
    __syncthreads();
    float* kb   = out;
    float* ksc  = out + 8000;
    float* klab = out + 10000;
    for (int s = lane; s < 100; s += 64) {
        klab[cls * 100 + s] = (float)(cls + 1);
        if (s < kept) {
            int r = keptlist[s];
            ((float4*)kb)[cls * 100 + s] =
                ((const float4*)sboxes)[(size_t)cls * 1024 + r];
            ksc[cls * 100 + s] = sscore[(size_t)cls * 1024 + r];
        } else {
            ((float4*)kb)[cls * 100 + s] = make_float4(0.f, 0.f, 0.f, 0.f);
            ksc[cls * 100 + s] = 0.f;
        }
    }
}

extern "C" void kernel_launch(void* const* d_in, const int* in_sizes, int n_in,
                              void* d_out, int out_size, void* d_ws, size_t ws_size,
                              hipStream_t stream)
{
    const float* feat  = (const float*)d_in[0];
    const float* prop  = (const float*)d_in[1];
    const float* w1    = (const float*)d_in[2];
    const float* b1    = (const float*)d_in[3];
    const float* w2    = (const float*)d_in[4];
    const float* b2    = (const float*)d_in[5];
    const float* w_cls = (const float*)d_in[6];
    const float* b_cls = (const float*)d_in[7];
    const float* w_box = (const float*)d_in[8];
    const float* b_box = (const float*)d_in[9];
    const int* img_h   = (const int*)d_in[10];
    const int* img_w   = (const int*)d_in[11];

    (void)hipFuncSetAttribute(reinterpret_cast<const void*>(gemm1_k),
                              hipFuncAttributeMaxDynamicSharedMemorySize, 98304);
    (void)hipFuncSetAttribute(reinterpret_cast<const void*>(gemm_g_k),
                              hipFuncAttributeMaxDynamicSharedMemorySize, 98304);

    char* wsb = (char*)d_ws;
    unsigned short* Apl = (unsigned short*)wsb;                    // 77,070,336 B
    unsigned short* Bpl = (unsigned short*)(wsb + 77070336);       // 77,070,336 B
    float* part = (float*)(wsb + 154140672);                       // 33,554,432 B
    // aliases into Apl (dead after gemm1):
    unsigned short* Ap2 = (unsigned short*)wsb;                    //  6,291,456 B
    unsigned short* Bt2 = (unsigned short*)(wsb + 6291456);        //  6,291,456 B
    unsigned short* Bth = (unsigned short*)(wsb + 12582912);       //    786,432 B
    unsigned short* Ah  = (unsigned short*)(wsb + 13369344);       //  6,291,456 B
    // post-GEMM small buffers:
    float* scores_m  = (float*)(wsb + 187695104);                  //     80,000 B
    float* boxes_dec = (float*)(wsb + 187775104);                  //    320,000 B
    float* Hout      = (float*)(wsb + 188095104);                  //    524,288 B
    // NMS scratch aliases part (dead after reduce_heads):
    unsigned long long* nmask = (unsigned long long*)(wsb + 154140672);
    float* sboxes = (float*)(wsb + 156762112);
    float* sscore = (float*)(wsb + 157089792);
    int*   Vcnt   = (int*)(wsb + 157171712);
    float* outp = (float*)d_out;

    hipLaunchKernelGGL(roi_align_split3, dim3(49, 1000), dim3(256), 0, stream,
                       feat, prop, Apl);
    hipLaunchKernelGGL(convT_k, dim3(196, 16), dim3(256), 0, stream,
                       w1, Bpl, 1, KDIM);
    hipLaunchKernelGGL(gemm1_k, dim3(512), dim3(256), 98304, stream,
                       Apl, Bpl, part);
    hipLaunchKernelGGL(reduce_split3_k, dim3(1000), dim3(256), 0, stream,
                       part, b1, Ap2, 8);
    hipLaunchKernelGGL(convT_k, dim3(16, 16), dim3(256), 0, stream,
                       w2, Bt2, 0, 1024);
    hipLaunchKernelGGL(conv_heads_k, dim3(512), dim3(256), 0, stream,
                       w_cls, w_box, Bth);
    hipLaunchKernelGGL(gemm_g_k, dim3(8, 8, 4), dim3(256), 98304, stream,
                       Ap2, Bt2, part, 1024, 256, 8, 1048576, 1048576, 1024);
    hipLaunchKernelGGL(reduce_split3_k, dim3(1000), dim3(256), 0, stream,
                       part, b2, Ah, 4);
    hipLaunchKernelGGL(gemm_g_k, dim3(1, 8, 8), dim3(256), 98304, stream,
                       Ah, Bth, part, 1024, 128, 4, 1048576, 131072, 128);
    hipLaunchKernelGGL(reduce_heads_k, dim3(1000), dim3(128), 0, stream,
                       part, b_cls, b_box, Hout);
    hipLaunchKernelGGL(postproc_k, dim3(1000), dim3(64), 0, stream,
                       Hout, prop, img_h, img_w, scores_m, boxes_dec);
    hipLaunchKernelGGL(nms_sort_k, dim3(20), dim3(256), 0, stream,
                       scores_m, boxes_dec, sboxes, sscore, Vcnt);
    hipLaunchKernelGGL(nms_mask_k, dim3(320), dim3(256), 0, stream, sboxes, nmask);
    hipLaunchKernelGGL(nms_sweep_k, dim3(20), dim3(64), 0, stream,
                       sboxes, sscore, Vcnt, nmask, outp);
}

// Round 8
// 416.084 us; speedup vs baseline: 2.2935x; 1.0643x over previous
//
#include <hip/hip_runtime.h>

// RoIHeads pipeline: roi_align -> FC1(relu) -> FC2(relu) -> cls/box heads ->
// softmax/decode/clip/mask -> per-class NMS.
//
// R8 (from R7 rocprof: dbuf 96KB -> 1 blk/CU killed occupancy, MfmaUtil 39%;
// swizzle verified conflicts=0):
//  - GEMM: back to single-buffer 48KB static LDS (3 blk/CU, R6 structure)
//    KEEPING the R7 T2 swizzle. A-fragments hoisted: 24 b128 reads/k-step
//    (was 36).
//  - reduce_heads + postproc fused (Hout in LDS).

#define NEGV -1000000000.0f

typedef __attribute__((ext_vector_type(8))) short short8v;  // 8 bf16 (4 VGPR)
typedef __attribute__((ext_vector_type(4))) float f32x4;

#define KDIM 12544
#define PL   (1024 * 12544)   // GEMM1 plane elems (1024 padded rows)

__device__ __forceinline__ unsigned short to_bf16(float f) {
    unsigned u = __float_as_uint(f);
    unsigned r = u + 0x7FFFu + ((u >> 16) & 1u);   // RNE
    return (unsigned short)(r >> 16);
}
__device__ __forceinline__ float bf2f(unsigned short s) {
    return __uint_as_float((unsigned)s << 16);
}
__device__ __forceinline__ void gload16(const void* gsrc, void* ldst) {
    __builtin_amdgcn_global_load_lds(
        (const __attribute__((address_space(1))) unsigned int*)gsrc,
        (__attribute__((address_space(3))) unsigned int*)ldst,
        16, 0, 0);
}

// ---------------- RoI align + 3-way bf16 split ----------------
__global__ __launch_bounds__(256) void roi_align_split3(const float* __restrict__ feat,
    const float* __restrict__ prop, unsigned short* __restrict__ Ap)
{
    int n = blockIdx.y;
    int p = blockIdx.x;
    int my = p / 7, mx = p % 7;
    float x1 = prop[n * 4 + 0] * 0.0625f;
    float y1 = prop[n * 4 + 1] * 0.0625f;
    float x2 = prop[n * 4 + 2] * 0.0625f;
    float y2 = prop[n * 4 + 3] * 0.0625f;
    float rw = fmaxf(x2 - x1, 1.0f), rh = fmaxf(y2 - y1, 1.0f);
    float y = y1 + ((float)my + 0.5f) * (rh / 7.0f);
    float x = x1 + ((float)mx + 0.5f) * (rw / 7.0f);
    bool oob = (y < -1.0f) || (y > 50.0f) || (x < -1.0f) || (x > 50.0f);
    y = fminf(fmaxf(y, 0.0f), 49.0f);
    x = fminf(fmaxf(x, 0.0f), 49.0f);
    int y0 = (int)floorf(y), x0 = (int)floorf(x);
    int y1i = min(y0 + 1, 49), x1i = min(x0 + 1, 49);
    float ly = y - (float)y0, lx = x - (float)x0;
    float hy = 1.0f - ly, hx = 1.0f - lx;
    int c = threadIdx.x;
    float v = feat[(y0 * 50 + x0) * 256 + c] * (hy * hx)
            + feat[(y0 * 50 + x1i) * 256 + c] * (hy * lx)
            + feat[(y1i * 50 + x0) * 256 + c] * (ly * hx)
            + feat[(y1i * 50 + x1i) * 256 + c] * (ly * lx);
    if (oob) v = 0.0f;
    unsigned short s1 = to_bf16(v);  float r  = v - bf2f(s1);
    unsigned short s2 = to_bf16(r);  float r2 = r - bf2f(s2);
    unsigned short s3 = to_bf16(r2);
    size_t o = (size_t)n * KDIM + p * 256 + c;
    Ap[o] = s1; Ap[PL + o] = s2; Ap[2 * (size_t)PL + o] = s3;
}

// ---------------- fp32 [K][1024] -> 3 bf16 planes, transposed [1024][Ktot] --
__global__ __launch_bounds__(256) void convT_k(const float* __restrict__ src,
    unsigned short* __restrict__ dst, int perm, int Ktot)
{
    __shared__ unsigned short T[3][64][72];
    int k0 = blockIdx.x * 64;
    int n0 = blockIdx.y * 64;
    int t = threadIdx.x;
    size_t plst = (size_t)1024 * Ktot;
#pragma unroll
    for (int j = 0; j < 16; ++j) {
        int idx = t + 256 * j;
        int n_l = idx & 63, k_l = idx >> 6;
        int kp = k0 + k_l;
        int orow = perm ? ((kp & 255) * 49 + (kp >> 8)) : kp;
        float v = src[(size_t)orow * 1024 + n0 + n_l];
        unsigned short s1 = to_bf16(v);  float r  = v - bf2f(s1);
        unsigned short s2 = to_bf16(r);  float r2 = r - bf2f(s2);
        T[0][k_l][n_l] = s1;
        T[1][k_l][n_l] = s2;
        T[2][k_l][n_l] = to_bf16(r2);
    }
    __syncthreads();
#pragma unroll
    for (int p = 0; p < 3; ++p)
#pragma unroll
        for (int jj = 0; jj < 2; ++jj) {
            int w = t + 256 * jj;
            int n_l = w >> 3, kg = w & 7;
            short8v pk;
#pragma unroll
            for (int e = 0; e < 8; ++e) pk[e] = (short)T[p][kg * 8 + e][n_l];
            *(short8v*)&dst[p * plst + (size_t)(n0 + n_l) * Ktot + k0 + kg * 8] = pk;
        }
}

// ---------------- packed heads weights -> 3 planes [128][1024] ----------
__global__ __launch_bounds__(256) void conv_heads_k(const float* __restrict__ w_cls,
    const float* __restrict__ w_box, unsigned short* __restrict__ Bth)
{
    int id = blockIdx.x * 256 + threadIdx.x;   // < 128*1024
    int j = id >> 10, k = id & 1023;
    float v = 0.f;
    if (j < 21) v = w_cls[k * 21 + j];
    else if (j < 105) v = w_box[k * 84 + (j - 21)];
    unsigned short s1 = to_bf16(v);  float r  = v - bf2f(s1);
    unsigned short s2 = to_bf16(r);  float r2 = r - bf2f(s2);
    Bth[id] = s1; Bth[131072 + id] = s2; Bth[262144 + id] = to_bf16(r2);
}

// ---------------- split-3 bf16 MFMA GEMM body (single-buf + T2 swizzle) ----
// A planes [1024][K], B planes [N][K], part[z][1024][N]. BM=BN=128, BK=32,
// 4 waves, 48KB LDS. Swizzle: slot(r,c) holds chunk c^((r>>1)&3) via
// pre-swizzled global source (rule #21); reads XOR the same term -> 2-way.
__device__ __forceinline__ void gemm_body(const unsigned short* __restrict__ Ap,
    const unsigned short* __restrict__ Bp, float* __restrict__ part,
    int K, int Ks, int nks, size_t plA, size_t plB, int N,
    int col0, int row0, int z, unsigned short* lds)
{
    int t = threadIdx.x;
    int w = t >> 6, lane = t & 63;
    int ln = lane & 15, g = lane >> 4;
    int wr = (w >> 1) * 64, wc = (w & 1) * 64;

    const unsigned short* smat = (w >= 2) ? Bp : Ap;
    size_t spl = (w >= 2) ? plB : plA;
    int sbase = (w >= 2) ? col0 : row0;
    int hoff = (w >= 2) ? 24576 : 0;
    int j0 = (w & 1) * 12;
    int srow = lane >> 2;
    int scol = ((lane & 3) ^ ((lane >> 3) & 3)) * 8;   // pre-swizzled source
    int kOff = z * Ks;

    const unsigned short* la  = lds;
    const unsigned short* lbB = lds + 12288;

    f32x4 acc[4][4] = {};
    for (int ks = 0; ks < nks; ++ks) {
        int kpos = kOff + (ks << 5) + scol;
        char* lb = (char*)lds + hoff;
#pragma unroll
        for (int ii = 0; ii < 12; ++ii) {
            int j = j0 + ii;
            int p = j >> 3, rb = j & 7;
            const unsigned short* src = smat + (size_t)p * spl
                + (size_t)(sbase + rb * 16 + srow) * K + kpos;
            gload16(src, lb + p * 8192 + rb * 1024);
        }
        __syncthreads();     // drains vmcnt -> tile ready

        short8v af[3][4];
#pragma unroll
        for (int pa = 0; pa < 3; ++pa)
#pragma unroll
            for (int fr = 0; fr < 4; ++fr) {
                int r = wr + fr * 16 + ln;
                af[pa][fr] = *(const short8v*)&la[pa * 4096 + r * 32 + ((g ^ ((r >> 1) & 3)) << 3)];
            }
#pragma unroll
        for (int pb = 0; pb < 3; ++pb) {
            short8v bf[4];
#pragma unroll
            for (int fc = 0; fc < 4; ++fc) {
                int r = wc + fc * 16 + ln;
                bf[fc] = *(const short8v*)&lbB[pb * 4096 + r * 32 + ((g ^ ((r >> 1) & 3)) << 3)];
            }
#pragma unroll
            for (int pa = 0; pa < 3 - pb; ++pa)
#pragma unroll
                for (int fr = 0; fr < 4; ++fr)
#pragma unroll
                    for (int fc = 0; fc < 4; ++fc)
                        acc[fr][fc] = __builtin_amdgcn_mfma_f32_16x16x32_bf16(
                            af[pa][fr], bf[fc], acc[fr][fc], 0, 0, 0);
        }
        __syncthreads();     // readers done before next overwrite
    }
    float* dst = part + (size_t)z * 1024 * N;
    int rbase = row0 + wr, cbase = col0 + wc;
#pragma unroll
    for (int fr = 0; fr < 4; ++fr)
#pragma unroll
        for (int fc = 0; fc < 4; ++fc)
#pragma unroll
            for (int reg = 0; reg < 4; ++reg)
                dst[(size_t)(rbase + fr * 16 + g * 4 + reg) * N + cbase + fc * 16 + ln] =
                    acc[fr][fc][reg];
}

// GEMM1 wrapper: 512 blocks 1D with XCD cluster swizzle (verified R5/R6).
__global__ __launch_bounds__(256, 3) void gemm1_k(const unsigned short* __restrict__ Ap,
    const unsigned short* __restrict__ Bp, float* __restrict__ part)
{
    __shared__ unsigned short lds[24576];
    int b = blockIdx.x;
    int xcd = b & 7;
    int rest = b >> 3;
    int m = rest & 7;
    int qhi = rest >> 3;
    int q = xcd + 8 * qhi;
    int z  = q >> 3;
    int qz = q & 7;
    int col0 = ((qz & 1) * 4 + (m & 3)) * 128;
    int row0 = ((qz >> 1) * 2 + (m >> 2)) * 128;
    gemm_body(Ap, Bp, part, KDIM, 1568, 49, (size_t)PL, (size_t)PL, 1024,
              col0, row0, z, lds);
}

// generic wrapper: grid (N/128, 8, S)
__global__ __launch_bounds__(256, 3) void gemm_g_k(const unsigned short* __restrict__ Ap,
    const unsigned short* __restrict__ Bp, float* __restrict__ part,
    int K, int Ks, int nks, int plA, int plB, int N)
{
    __shared__ unsigned short lds[24576];
    gemm_body(Ap, Bp, part, K, Ks, nks, (size_t)plA, (size_t)plB, N,
              blockIdx.x * 128, blockIdx.y * 128, blockIdx.z, lds);
}

// ---------------- split-K reduce + bias + relu -> split-3 planes ----------
__global__ __launch_bounds__(256) void reduce_split3_k(const float* __restrict__ part,
    const float* __restrict__ bias, unsigned short* __restrict__ dstP, int S)
{
    int m = blockIdx.x, t = threadIdx.x;
    size_t o = (size_t)m * 1024 + t * 4;
    float4 acc = *(const float4*)&part[o];
    for (int s = 1; s < S; ++s) {
        float4 p = *(const float4*)&part[(size_t)s * 1048576 + o];
        acc.x += p.x; acc.y += p.y; acc.z += p.z; acc.w += p.w;
    }
    float4 bv = *(const float4*)&bias[t * 4];
    float vals[4] = { fmaxf(acc.x + bv.x, 0.f), fmaxf(acc.y + bv.y, 0.f),
                      fmaxf(acc.z + bv.z, 0.f), fmaxf(acc.w + bv.w, 0.f) };
    unsigned short o1[4], o2[4], o3[4];
#pragma unroll
    for (int e = 0; e < 4; ++e) {
        unsigned short s1 = to_bf16(vals[e]);  float r  = vals[e] - bf2f(s1);
        unsigned short s2 = to_bf16(r);        float r2 = r - bf2f(s2);
        o1[e] = s1; o2[e] = s2; o3[e] = to_bf16(r2);
    }
    *(uint2*)&dstP[o]           = *(uint2*)o1;
    *(uint2*)&dstP[1048576 + o] = *(uint2*)o2;
    *(uint2*)&dstP[2097152 + o] = *(uint2*)o3;
}

// ---------------- fused heads reduce + softmax/decode/clip/mask ----------
// grid 1000 x 128 thr: sum 8 partials + bias -> hn[128] in LDS; threads
// 1..20 then run per-class postproc for this n.
__global__ __launch_bounds__(128) void heads_post_k(const float* __restrict__ part,
    const float* __restrict__ b_cls, const float* __restrict__ b_box,
    const float* __restrict__ prop, const int* __restrict__ img_h_p,
    const int* __restrict__ img_w_p, float* __restrict__ scores_m,
    float* __restrict__ boxes_dec)
{
    __shared__ float hn[128];
    int n = blockIdx.x, t = threadIdx.x;
    size_t o = (size_t)n * 128 + t;
    float a = part[o];
    for (int s = 1; s < 8; ++s) a += part[(size_t)s * 131072 + o];
    float b = (t < 21) ? b_cls[t] : (t < 105 ? b_box[t - 21] : 0.f);
    hn[t] = a + b;
    __syncthreads();
    int cls = t;
    if (cls < 1 || cls > 20) return;
    float mx = -3.0e38f;
    for (int i = 0; i < 21; ++i) mx = fmaxf(mx, hn[i]);
    float sum = 0.f;
    for (int i = 0; i < 21; ++i) sum += expf(hn[i] - mx);
    float score = expf(hn[cls] - mx) / sum;

    float p0 = prop[n * 4 + 0], p1 = prop[n * 4 + 1];
    float p2 = prop[n * 4 + 2], p3 = prop[n * 4 + 3];
    float w = p2 - p0, h = p3 - p1;
    float cx = p0 + 0.5f * w, cy = p1 + 0.5f * h;
    float d0 = hn[21 + cls * 4 + 0];
    float d1 = hn[21 + cls * 4 + 1];
    float d2 = hn[21 + cls * 4 + 2];
    float d3 = hn[21 + cls * 4 + 3];
    const float CLIP = 4.135166556742356f;  // log(1000/16)
    float dx = d0 / 10.0f, dy = d1 / 10.0f;
    float dw = fminf(d2 / 5.0f, CLIP), dh = fminf(d3 / 5.0f, CLIP);
    float pcx = dx * w + cx, pcy = dy * h + cy;
    float pw = expf(dw) * w, ph = expf(dh) * h;
    float bx1 = pcx - 0.5f * pw, by1 = pcy - 0.5f * ph;
    float bx2 = pcx + 0.5f * pw, by2 = pcy + 0.5f * ph;
    float iw = (float)img_w_p[0], ih = (float)img_h_p[0];
    bx1 = fminf(fmaxf(bx1, 0.f), iw);
    by1 = fminf(fmaxf(by1, 0.f), ih);
    bx2 = fminf(fmaxf(bx2, 0.f), iw);
    by2 = fminf(fmaxf(by2, 0.f), ih);
    float bw = bx2 - bx1, bh = by2 - by1;
    bool keep = (bw >= 1.0f) && (bh >= 1.0f) && (score >= 0.05f);
    int oo = (cls - 1) * 1000 + n;
    scores_m[oo] = keep ? score : NEGV;
    ((float4*)boxes_dec)[oo] = make_float4(bx1, by1, bx2, by2);
}

// ---------------- NMS stage 1: bitonic sort by (score desc, idx asc) -------
__global__ __launch_bounds__(256) void nms_sort_k(const float* __restrict__ scores_m,
    const float* __restrict__ boxes_dec, float* __restrict__ sboxes,
    float* __restrict__ sscore, int* __restrict__ Vcnt)
{
    __shared__ unsigned long long sk[1024];
    __shared__ int cnt;
    int cls = blockIdx.x, t = threadIdx.x;
    if (t == 0) cnt = 0;
    __syncthreads();
    for (int r = t; r < 1024; r += 256) {
        unsigned long long inv = ~0ull;
        if (r < 1000) {
            float v = scores_m[cls * 1000 + r];
            unsigned ub = __float_as_uint(v);
            ub = (ub & 0x80000000u) ? ~ub : (ub | 0x80000000u);
            inv = ~(((unsigned long long)ub << 32) | (unsigned)(1023 - r));
            if (v > 0.5f * NEGV) atomicAdd(&cnt, 1);
        }
        sk[r] = inv;
    }
    __syncthreads();
    for (int k = 2; k <= 1024; k <<= 1) {
        for (int j = k >> 1; j > 0; j >>= 1) {
            for (int pi = t; pi < 512; pi += 256) {
                int i = ((pi & ~(j - 1)) << 1) | (pi & (j - 1));
                int p = i | j;
                bool up = ((i & k) == 0);
                unsigned long long a = sk[i], b2 = sk[p];
                if ((a > b2) == up) { sk[i] = b2; sk[p] = a; }
            }
            __syncthreads();
        }
    }
    for (int r = t; r < 1024; r += 256) {
        unsigned long long key = ~sk[r];
        unsigned ub = (unsigned)(key >> 32);
        int idx = 1023 - (int)(key & 1023u);
        float4 bx = make_float4(0.f, 0.f, 0.f, 0.f);
        float scv = NEGV;
        if (key != 0ull && idx < 1000) {
            bx = ((const float4*)boxes_dec)[cls * 1000 + idx];
            unsigned u = (ub & 0x80000000u) ? (ub & 0x7FFFFFFFu) : ~ub;
            scv = __uint_as_float(u);
        }
        ((float4*)sboxes)[(size_t)cls * 1024 + r] = bx;
        sscore[(size_t)cls * 1024 + r] = scv;
    }
    if (t == 0) Vcnt[cls] = cnt;
}

// ---------------- NMS stage 2: IoU bitmask rows ----------------
__global__ __launch_bounds__(256) void nms_mask_k(const float* __restrict__ sboxes,
    unsigned long long* __restrict__ mask)
{
    __shared__ float4 colb[1024];
    __shared__ float area[1024];
    int cls = blockIdx.x >> 4;
    int chunk = blockIdx.x & 15;
    int t = threadIdx.x;
    const float4* sb = (const float4*)sboxes + (size_t)cls * 1024;
    for (int j = t; j < 1024; j += 256) {
        float4 b = sb[j];
        colb[j] = b;
        area[j] = (b.z - b.x) * (b.w - b.y);
    }
    __syncthreads();
    int row_l = t >> 2;
    int qt = t & 3;
    int i = chunk * 64 + row_l;
    float4 rb = colb[i];
    float a1 = area[i];
    unsigned long long* dst = mask + ((size_t)cls * 1024 + i) * 16 + qt * 4;
#pragma unroll
    for (int w = 0; w < 4; ++w) {
        unsigned long long wv = 0;
        int jb = qt * 256 + w * 64;
#pragma unroll 8
        for (int bi = 0; bi < 64; ++bi) {
            int j = jb + bi;
            float4 cb = colb[j];
            float ltx = fmaxf(rb.x, cb.x), lty = fmaxf(rb.y, cb.y);
            float rbx = fminf(rb.z, cb.z), rby = fminf(rb.w, cb.w);
            float wiw = fmaxf(rbx - ltx, 0.f), wih = fmaxf(rby - lty, 0.f);
            float inter = wiw * wih;
            float iou = inter / (a1 + area[j] - inter + 1e-9f);
            if (j > i && iou > 0.5f) wv |= (1ull << bi);
        }
        dst[w] = wv;
    }
}

// ---------------- NMS stage 3: greedy sweep ----------------
__global__ __launch_bounds__(64) void nms_sweep_k(const float* __restrict__ sboxes,
    const float* __restrict__ sscore, const int* __restrict__ Vcnt,
    const unsigned long long* __restrict__ mask, float* __restrict__ out)
{
    int cls = blockIdx.x;
    int lane = threadIdx.x;
    __shared__ int keptlist[100];
    int V = Vcnt[cls];
    const unsigned long long* mbase = mask + (size_t)cls * 1024 * 16;
    unsigned long long suppr = 0;
    int kept = 0;
    int nb = (V + 15) >> 4;
    for (int b = 0; b < nb && kept < 100; ++b) {
        unsigned long long L[16];
#pragma unroll
        for (int k = 0; k < 16; ++k)
            L[k] = mbase[(size_t)(b * 16 + k) * 16 + (lane & 15)];
#pragma unroll
        for (int k = 0; k < 16; ++k) {
            int i = b * 16 + k;
            if (i < V && kept < 100) {
                bool sup = (lane == (i >> 6)) && ((suppr >> (i & 63)) & 1ull);
                if (__ballot(sup) == 0ull) {
                    if (lane == 0) keptlist[kept] = i;
                    if (lane < 16) suppr |= L[k];
                    ++kept;
                }
            }
        }
    }
    __syncthreads();
    float* kb   = out;
    float* ksc  = out + 8000;
    float* klab = out + 10000;
    for (int s = lane; s < 100; s += 64) {
        klab[cls * 100 + s] = (float)(cls + 1);
        if (s < kept) {
            int r = keptlist[s];
            ((float4*)kb)[cls * 100 + s] =
                ((const float4*)sboxes)[(size_t)cls * 1024 + r];
            ksc[cls * 100 + s] = sscore[(size_t)cls * 1024 + r];
        } else {
            ((float4*)kb)[cls * 100 + s] = make_float4(0.f, 0.f, 0.f, 0.f);
            ksc[cls * 100 + s] = 0.f;
        }
    }
}

extern "C" void kernel_launch(void* const* d_in, const int* in_sizes, int n_in,
                              void* d_out, int out_size, void* d_ws, size_t ws_size,
                              hipStream_t stream)
{
    const float* feat  = (const float*)d_in[0];
    const float* prop  = (const float*)d_in[1];
    const float* w1    = (const float*)d_in[2];
    const float* b1    = (const float*)d_in[3];
    const float* w2    = (const float*)d_in[4];
    const float* b2    = (const float*)d_in[5];
    const float* w_cls = (const float*)d_in[6];
    const float* b_cls = (const float*)d_in[7];
    const float* w_box = (const float*)d_in[8];
    const float* b_box = (const float*)d_in[9];
    const int* img_h   = (const int*)d_in[10];
    const int* img_w   = (const int*)d_in[11];

    char* wsb = (char*)d_ws;
    unsigned short* Apl = (unsigned short*)wsb;                    // 77,070,336 B
    unsigned short* Bpl = (unsigned short*)(wsb + 77070336);       // 77,070,336 B
    float* part = (float*)(wsb + 154140672);                       // 33,554,432 B
    // aliases into Apl (dead after gemm1):
    unsigned short* Ap2 = (unsigned short*)wsb;                    //  6,291,456 B
    unsigned short* Bt2 = (unsigned short*)(wsb + 6291456);        //  6,291,456 B
    unsigned short* Bth = (unsigned short*)(wsb + 12582912);       //    786,432 B
    unsigned short* Ah  = (unsigned short*)(wsb + 13369344);       //  6,291,456 B
    // post-GEMM small buffers:
    float* scores_m  = (float*)(wsb + 187695104);                  //     80,000 B
    float* boxes_dec = (float*)(wsb + 187775104);                  //    320,000 B
    // NMS scratch aliases part (dead after heads_post):
    unsigned long long* nmask = (unsigned long long*)(wsb + 154140672);
    float* sboxes = (float*)(wsb + 156762112);
    float* sscore = (float*)(wsb + 157089792);
    int*   Vcnt   = (int*)(wsb + 157171712);
    float* outp = (float*)d_out;

    hipLaunchKernelGGL(roi_align_split3, dim3(49, 1000), dim3(256), 0, stream,
                       feat, prop, Apl);
    hipLaunchKernelGGL(convT_k, dim3(196, 16), dim3(256), 0, stream,
                       w1, Bpl, 1, KDIM);
    hipLaunchKernelGGL(gemm1_k, dim3(512), dim3(256), 0, stream,
                       Apl, Bpl, part);
    hipLaunchKernelGGL(reduce_split3_k, dim3(1000), dim3(256), 0, stream,
                       part, b1, Ap2, 8);
    hipLaunchKernelGGL(convT_k, dim3(16, 16), dim3(256), 0, stream,
                       w2, Bt2, 0, 1024);
    hipLaunchKernelGGL(conv_heads_k, dim3(512), dim3(256), 0, stream,
                       w_cls, w_box, Bth);
    hipLaunchKernelGGL(gemm_g_k, dim3(8, 8, 4), dim3(256), 0, stream,
                       Ap2, Bt2, part, 1024, 256, 8, 1048576, 1048576, 1024);
    hipLaunchKernelGGL(reduce_split3_k, dim3(1000), dim3(256), 0, stream,
                       part, b2, Ah, 4);
    hipLaunchKernelGGL(gemm_g_k, dim3(1, 8, 8), dim3(256), 0, stream,
                       Ah, Bth, part, 1024, 128, 4, 1048576, 131072, 128);
    hipLaunchKernelGGL(heads_post_k, dim3(1000), dim3(128), 0, stream,
                       part, b_cls, b_box, prop, img_h, img_w, scores_m, boxes_dec);
    hipLaunchKernelGGL(nms_sort_k, dim3(20), dim3(256), 0, stream,
                       scores_m, boxes_dec, sboxes, sscore, Vcnt);
    hipLaunchKernelGGL(nms_mask_k, dim3(320), dim3(256), 0, stream, sboxes, nmask);
    hipLaunchKernelGGL(nms_sweep_k, dim3(20), dim3(64), 0, stream,
                       sboxes, sscore, Vcnt, nmask, outp);
}